// Round 1
// baseline (1687.818 us; speedup 1.0000x reference)
//
#include <hip/hip_runtime.h>
#include <hip/hip_bf16.h>
#include <math.h>

#define N_NODES_MAX 20000

// ---------------- degree / norm ----------------
__global__ void deg_kernel(const int* __restrict__ dst, float* __restrict__ deg, int E) {
    int e = blockIdx.x * blockDim.x + threadIdx.x;
    if (e < E) atomicAdd(&deg[dst[e]], 1.0f);
}

__global__ void dinv_kernel(float* __restrict__ deg, int N) {
    int i = blockIdx.x * blockDim.x + threadIdx.x;
    if (i < N) deg[i] = rsqrtf(deg[i] + 1.0f);   // +1 self-loop; deg>=1 always
}

// ---------------- fp32 tiled GEMM: C[N,M] = A[N,K] @ B[K,M] ----------------
// 64x64 tile, BK=16, 256 threads, 4x4 per thread. K multiple of 16, M multiple of 64.
__global__ __launch_bounds__(256) void gemm_tile(const float* __restrict__ A,
                                                 const float* __restrict__ B,
                                                 float* __restrict__ C,
                                                 int N, int K, int M) {
    __shared__ float As[16][64];
    __shared__ float Bs[16][64];
    int tid = threadIdx.x;
    int tx = tid & 15, ty = tid >> 4;
    int r0 = blockIdx.y * 64, c0 = blockIdx.x * 64;
    float acc[4][4] = {};
    for (int kb = 0; kb < K; kb += 16) {
#pragma unroll
        for (int l = 0; l < 4; l++) {
            int idx = tid + l * 256;
            int row = idx >> 4, kk = idx & 15;
            As[kk][row] = (r0 + row < N) ? A[(size_t)(r0 + row) * K + kb + kk] : 0.f;
        }
#pragma unroll
        for (int l = 0; l < 4; l++) {
            int idx = tid + l * 256;
            int kk = idx >> 6, col = idx & 63;
            Bs[kk][col] = B[(size_t)(kb + kk) * M + c0 + col];
        }
        __syncthreads();
#pragma unroll
        for (int kk = 0; kk < 16; kk++) {
            float a[4], b[4];
#pragma unroll
            for (int i = 0; i < 4; i++) a[i] = As[kk][ty * 4 + i];
#pragma unroll
            for (int j = 0; j < 4; j++) b[j] = Bs[kk][tx * 4 + j];
#pragma unroll
            for (int i = 0; i < 4; i++)
#pragma unroll
                for (int j = 0; j < 4; j++) acc[i][j] += a[i] * b[j];
        }
        __syncthreads();
    }
#pragma unroll
    for (int i = 0; i < 4; i++) {
        int r = r0 + ty * 4 + i;
        if (r < N) {
#pragma unroll
            for (int j = 0; j < 4; j++)
                C[(size_t)r * M + c0 + tx * 4 + j] = acc[i][j];
        }
    }
}

// ---------------- self-loop init: out[i][c] = h[i][c] * dinv[i]^2 ----------------
__global__ void selfinit_kernel(const float* __restrict__ h, const float* __restrict__ dinv,
                                float* __restrict__ out, int N, int shiftC) {
    size_t idx = (size_t)blockIdx.x * blockDim.x + threadIdx.x;
    size_t total = (size_t)N << shiftC;
    if (idx >= total) return;
    int i = (int)(idx >> shiftC);
    float di = dinv[i];
    out[idx] = h[idx] * di * di;
}

// ---------------- edge scatter, 256 channels: one wave per edge ----------------
__global__ void scatter256_kernel(const float* __restrict__ h, const int* __restrict__ src,
                                  const int* __restrict__ dst, const float* __restrict__ dinv,
                                  float* __restrict__ out, int E) {
    int e = blockIdx.x * (blockDim.x >> 6) + (threadIdx.x >> 6);
    if (e >= E) return;
    int lane = threadIdx.x & 63;
    int s = src[e], d = dst[e];
    float norm = dinv[s] * dinv[d];
    float4 v = ((const float4*)(h + (size_t)s * 256))[lane];
    float* od = out + (size_t)d * 256 + lane * 4;
    atomicAdd(od + 0, v.x * norm);
    atomicAdd(od + 1, v.y * norm);
    atomicAdd(od + 2, v.z * norm);
    atomicAdd(od + 3, v.w * norm);
}

// ---------------- edge scatter, 128 channels ----------------
__global__ void scatter128_kernel(const float* __restrict__ h, const int* __restrict__ src,
                                  const int* __restrict__ dst, const float* __restrict__ dinv,
                                  float* __restrict__ out, int E) {
    int e = blockIdx.x * (blockDim.x >> 6) + (threadIdx.x >> 6);
    if (e >= E) return;
    int lane = threadIdx.x & 63;
    int s = src[e], d = dst[e];
    float norm = dinv[s] * dinv[d];
    float2 v = ((const float2*)(h + (size_t)s * 128))[lane];
    float* od = out + (size_t)d * 128 + lane * 2;
    atomicAdd(od + 0, v.x * norm);
    atomicAdd(od + 1, v.y * norm);
}

// ---------------- epilogue 1: in-place bias + relu (C=256) ----------------
__global__ void epi1_kernel(float* __restrict__ out, const float* __restrict__ b, size_t total) {
    size_t idx = (size_t)blockIdx.x * blockDim.x + threadIdx.x;
    if (idx >= total) return;
    out[idx] = fmaxf(out[idx] + b[idx & 255], 0.f);
}

// ---------------- epilogue 2 + mean-pool accumulate (C=128) ----------------
__global__ void epi2_pool_kernel(const float* __restrict__ out2, const float* __restrict__ b2,
                                 const int* __restrict__ batch, float* __restrict__ gsum,
                                 float* __restrict__ gcnt, int N) {
    int node = blockIdx.x * (blockDim.x >> 6) + (threadIdx.x >> 6);
    if (node >= N) return;
    int lane = threadIdx.x & 63;
    int g = batch[node];
    float2 v = ((const float2*)(out2 + (size_t)node * 128))[lane];
    float2 b = ((const float2*)b2)[lane];
    float r0 = fmaxf(v.x + b.x, 0.f);
    float r1 = fmaxf(v.y + b.y, 0.f);
    atomicAdd(gsum + g * 128 + lane * 2 + 0, r0);
    atomicAdd(gsum + g * 128 + lane * 2 + 1, r1);
    if (lane == 0) atomicAdd(gcnt + g, 1.0f);
}

// ---------------- head: mean, FC64+relu, FC1+sigmoid ----------------
__global__ void head_kernel(const float* __restrict__ gsum, const float* __restrict__ gcnt,
                            const float* __restrict__ Wl1, const float* __restrict__ bl1,
                            const float* __restrict__ Wl2, const float* __restrict__ bl2,
                            float* __restrict__ out) {
    int g = blockIdx.x;
    int t = threadIdx.x;  // 64 threads
    __shared__ float gv[128];
    float cnt = fmaxf(gcnt[g], 1.0f);
    gv[t]      = gsum[g * 128 + t] / cnt;
    gv[t + 64] = gsum[g * 128 + 64 + t] / cnt;
    __syncthreads();
    float acc = bl1[t];
    for (int k = 0; k < 128; k++) acc += gv[k] * Wl1[k * 64 + t];
    acc = fmaxf(acc, 0.f);
    float p = acc * Wl2[t];
#pragma unroll
    for (int off = 32; off; off >>= 1) p += __shfl_down(p, off);
    if (t == 0) out[g] = 1.f / (1.f + expf(-(p + bl2[0])));
}

extern "C" void kernel_launch(void* const* d_in, const int* in_sizes, int n_in,
                              void* d_out, int out_size, void* d_ws, size_t ws_size,
                              hipStream_t stream) {
    const float* x   = (const float*)d_in[0];
    const int* ei    = (const int*)d_in[1];
    const int* batch = (const int*)d_in[2];
    const float* W1  = (const float*)d_in[3];
    const float* b1  = (const float*)d_in[4];
    const float* W2  = (const float*)d_in[5];
    const float* b2  = (const float*)d_in[6];
    const float* Wl1 = (const float*)d_in[7];
    const float* bl1 = (const float*)d_in[8];
    const float* Wl2 = (const float*)d_in[9];
    const float* bl2 = (const float*)d_in[10];
    float* out = (float*)d_out;

    const int N = in_sizes[2];         // 20000
    const int E = in_sizes[1] / 2;     // 320000
    const int G = 64;
    const int* src = ei;
    const int* dst = ei + E;

    // ---- workspace layout (floats) ----
    float* ws = (float*)d_ws;
    float* deg  = ws;                  // N (reused as dinv)
    float* gsum = ws + N;              // G*128 = 8192
    float* gcnt = gsum + G * 128;      // G
    size_t zero_floats = (size_t)N + G * 128 + G;
    float* h    = ws + ((zero_floats + 1023) & ~(size_t)1023);  // N*256
    float* out1 = h    + (size_t)N * 256;                       // N*256
    float* t    = out1 + (size_t)N * 256;                       // N*128
    float* out2 = t    + (size_t)N * 128;                       // N*128

    // zero deg/gsum/gcnt in one shot
    hipMemsetAsync(ws, 0, zero_floats * sizeof(float), stream);

    // degrees + dinv
    deg_kernel<<<(E + 255) / 256, 256, 0, stream>>>(dst, deg, E);
    dinv_kernel<<<(N + 255) / 256, 256, 0, stream>>>(deg, N);

    // layer 1: h = x @ W1
    {
        dim3 grid(256 / 64, (N + 63) / 64);
        gemm_tile<<<grid, 256, 0, stream>>>(x, W1, h, N, 256, 256);
    }
    // out1 = selfloop + scatter
    {
        size_t total = (size_t)N * 256;
        selfinit_kernel<<<(int)((total + 255) / 256), 256, 0, stream>>>(h, deg, out1, N, 8);
        scatter256_kernel<<<(E + 3) / 4, 256, 0, stream>>>(h, src, dst, deg, out1, E);
        epi1_kernel<<<(int)((total + 255) / 256), 256, 0, stream>>>(out1, b1, total);
    }
    // layer 2: t = out1 @ W2
    {
        dim3 grid(128 / 64, (N + 63) / 64);
        gemm_tile<<<grid, 256, 0, stream>>>(out1, W2, t, N, 256, 128);
    }
    {
        size_t total = (size_t)N * 128;
        selfinit_kernel<<<(int)((total + 255) / 256), 256, 0, stream>>>(t, deg, out2, N, 7);
        scatter128_kernel<<<(E + 3) / 4, 256, 0, stream>>>(t, src, dst, deg, out2, E);
        epi2_pool_kernel<<<(N + 3) / 4, 256, 0, stream>>>(out2, b2, batch, gsum, gcnt, N);
    }
    // head
    head_kernel<<<G, 64, 0, stream>>>(gsum, gcnt, Wl1, bl1, Wl2, bl2, out);
}

// Round 2
// 460.465 us; speedup vs baseline: 3.6655x; 3.6655x over previous
//
#include <hip/hip_runtime.h>
#include <hip/hip_bf16.h>
#include <math.h>

// ---------------- degree histogram (int) ----------------
__global__ void deg_kernel(const int* __restrict__ dst, int* __restrict__ deg, int E) {
    int e = blockIdx.x * blockDim.x + threadIdx.x;
    if (e < E) atomicAdd(&deg[dst[e]], 1);
}

__global__ void dinv_kernel(const int* __restrict__ deg, float* __restrict__ dinv, int N) {
    int i = blockIdx.x * blockDim.x + threadIdx.x;
    if (i < N) dinv[i] = rsqrtf((float)deg[i] + 1.0f);   // +1 self-loop
}

// ---------------- exclusive prefix scan of deg -> rowptr (single block) ----------------
__global__ __launch_bounds__(256) void scan_kernel(const int* __restrict__ deg,
                                                   int* __restrict__ rowptr, int N) {
    __shared__ int sums[256];
    int t = threadIdx.x;
    int chunk = (N + 255) / 256;
    int start = t * chunk;
    int end = start + chunk; if (end > N) end = N; if (start > N) start = N;
    int s = 0;
    for (int i = start; i < end; i++) s += deg[i];
    sums[t] = s;
    __syncthreads();
    for (int off = 1; off < 256; off <<= 1) {
        int v = (t >= off) ? sums[t - off] : 0;
        __syncthreads();
        sums[t] += v;
        __syncthreads();
    }
    int run = (t == 0) ? 0 : sums[t - 1];
    for (int i = start; i < end; i++) { rowptr[i] = run; run += deg[i]; }
    if (t == 255) rowptr[N] = run;
}

// ---------------- CSR fill ----------------
__global__ void fill_kernel(const int* __restrict__ src, const int* __restrict__ dst,
                            const int* __restrict__ rowptr, int* __restrict__ fill,
                            int* __restrict__ csr_src, int E) {
    int e = blockIdx.x * blockDim.x + threadIdx.x;
    if (e >= E) return;
    int d = dst[e];
    int pos = rowptr[d] + atomicAdd(&fill[d], 1);
    csr_src[pos] = src[e];
}

// ---------------- fp32 tiled GEMM: C[N,M] = A[N,K] @ B[K,M] ----------------
__global__ __launch_bounds__(256) void gemm_tile(const float* __restrict__ A,
                                                 const float* __restrict__ B,
                                                 float* __restrict__ C,
                                                 int N, int K, int M) {
    __shared__ float As[16][64];
    __shared__ float Bs[16][64];
    int tid = threadIdx.x;
    int tx = tid & 15, ty = tid >> 4;
    int r0 = blockIdx.y * 64, c0 = blockIdx.x * 64;
    float acc[4][4] = {};
    for (int kb = 0; kb < K; kb += 16) {
#pragma unroll
        for (int l = 0; l < 4; l++) {
            int idx = tid + l * 256;
            int row = idx >> 4, kk = idx & 15;
            As[kk][row] = (r0 + row < N) ? A[(size_t)(r0 + row) * K + kb + kk] : 0.f;
        }
#pragma unroll
        for (int l = 0; l < 4; l++) {
            int idx = tid + l * 256;
            int kk = idx >> 6, col = idx & 63;
            Bs[kk][col] = B[(size_t)(kb + kk) * M + c0 + col];
        }
        __syncthreads();
#pragma unroll
        for (int kk = 0; kk < 16; kk++) {
            float a[4], b[4];
#pragma unroll
            for (int i = 0; i < 4; i++) a[i] = As[kk][ty * 4 + i];
#pragma unroll
            for (int j = 0; j < 4; j++) b[j] = Bs[kk][tx * 4 + j];
#pragma unroll
            for (int i = 0; i < 4; i++)
#pragma unroll
                for (int j = 0; j < 4; j++) acc[i][j] += a[i] * b[j];
        }
        __syncthreads();
    }
#pragma unroll
    for (int i = 0; i < 4; i++) {
        int r = r0 + ty * 4 + i;
        if (r < N) {
#pragma unroll
            for (int j = 0; j < 4; j++)
                C[(size_t)r * M + c0 + tx * 4 + j] = acc[i][j];
        }
    }
}

// ---------------- gather aggregate, 256 ch: one wave per dst node ----------------
// out1[d] = relu( dinv[d] * ( sum_s h[s]*dinv[s] + h[d]*dinv[d] ) + b )
__global__ __launch_bounds__(256) void gather256_kernel(const float* __restrict__ h,
                                                        const int* __restrict__ csr_src,
                                                        const int* __restrict__ rowptr,
                                                        const float* __restrict__ dinv,
                                                        const float* __restrict__ bias,
                                                        float* __restrict__ out, int N) {
    int node = blockIdx.x * 4 + (threadIdx.x >> 6);
    if (node >= N) return;
    int lane = threadIdx.x & 63;
    int beg = rowptr[node], end = rowptr[node + 1];
    float4 acc0 = {0, 0, 0, 0}, acc1 = {0, 0, 0, 0};
    int j = beg;
    for (; j + 1 < end; j += 2) {
        int s0 = csr_src[j], s1 = csr_src[j + 1];
        float w0 = dinv[s0], w1 = dinv[s1];
        float4 v0 = ((const float4*)(h + (size_t)s0 * 256))[lane];
        float4 v1 = ((const float4*)(h + (size_t)s1 * 256))[lane];
        acc0.x += v0.x * w0; acc0.y += v0.y * w0; acc0.z += v0.z * w0; acc0.w += v0.w * w0;
        acc1.x += v1.x * w1; acc1.y += v1.y * w1; acc1.z += v1.z * w1; acc1.w += v1.w * w1;
    }
    if (j < end) {
        int s0 = csr_src[j];
        float w0 = dinv[s0];
        float4 v0 = ((const float4*)(h + (size_t)s0 * 256))[lane];
        acc0.x += v0.x * w0; acc0.y += v0.y * w0; acc0.z += v0.z * w0; acc0.w += v0.w * w0;
    }
    float dd = dinv[node];
    float4 hv = ((const float4*)(h + (size_t)node * 256))[lane];
    float4 bv = ((const float4*)bias)[lane];
    float4 r;
    r.x = fmaxf((acc0.x + acc1.x + hv.x * dd) * dd + bv.x, 0.f);
    r.y = fmaxf((acc0.y + acc1.y + hv.y * dd) * dd + bv.y, 0.f);
    r.z = fmaxf((acc0.z + acc1.z + hv.z * dd) * dd + bv.z, 0.f);
    r.w = fmaxf((acc0.w + acc1.w + hv.w * dd) * dd + bv.w, 0.f);
    ((float4*)(out + (size_t)node * 256))[lane] = r;
}

// ---------------- gather aggregate + pool, 128 ch: one wave per dst node ----------------
__global__ __launch_bounds__(256) void gather128_pool_kernel(const float* __restrict__ t,
                                                             const int* __restrict__ csr_src,
                                                             const int* __restrict__ rowptr,
                                                             const float* __restrict__ dinv,
                                                             const float* __restrict__ bias,
                                                             const int* __restrict__ batch,
                                                             float* __restrict__ gsum,
                                                             float* __restrict__ gcnt, int N) {
    int node = blockIdx.x * 4 + (threadIdx.x >> 6);
    if (node >= N) return;
    int lane = threadIdx.x & 63;
    int beg = rowptr[node], end = rowptr[node + 1];
    float2 acc0 = {0, 0}, acc1 = {0, 0};
    int j = beg;
    for (; j + 1 < end; j += 2) {
        int s0 = csr_src[j], s1 = csr_src[j + 1];
        float w0 = dinv[s0], w1 = dinv[s1];
        float2 v0 = ((const float2*)(t + (size_t)s0 * 128))[lane];
        float2 v1 = ((const float2*)(t + (size_t)s1 * 128))[lane];
        acc0.x += v0.x * w0; acc0.y += v0.y * w0;
        acc1.x += v1.x * w1; acc1.y += v1.y * w1;
    }
    if (j < end) {
        int s0 = csr_src[j];
        float w0 = dinv[s0];
        float2 v0 = ((const float2*)(t + (size_t)s0 * 128))[lane];
        acc0.x += v0.x * w0; acc0.y += v0.y * w0;
    }
    float dd = dinv[node];
    float2 hv = ((const float2*)(t + (size_t)node * 128))[lane];
    float2 bv = ((const float2*)bias)[lane];
    float r0 = fmaxf((acc0.x + acc1.x + hv.x * dd) * dd + bv.x, 0.f);
    float r1 = fmaxf((acc0.y + acc1.y + hv.y * dd) * dd + bv.y, 0.f);
    int g = batch[node];
    atomicAdd(gsum + g * 128 + lane * 2 + 0, r0);
    atomicAdd(gsum + g * 128 + lane * 2 + 1, r1);
    if (lane == 0) atomicAdd(gcnt + g, 1.0f);
}

// ---------------- head: mean, FC64+relu, FC1+sigmoid ----------------
__global__ void head_kernel(const float* __restrict__ gsum, const float* __restrict__ gcnt,
                            const float* __restrict__ Wl1, const float* __restrict__ bl1,
                            const float* __restrict__ Wl2, const float* __restrict__ bl2,
                            float* __restrict__ out) {
    int g = blockIdx.x;
    int t = threadIdx.x;  // 64 threads
    __shared__ float gv[128];
    float cnt = fmaxf(gcnt[g], 1.0f);
    gv[t]      = gsum[g * 128 + t] / cnt;
    gv[t + 64] = gsum[g * 128 + 64 + t] / cnt;
    __syncthreads();
    float acc = bl1[t];
    for (int k = 0; k < 128; k++) acc += gv[k] * Wl1[k * 64 + t];
    acc = fmaxf(acc, 0.f);
    float p = acc * Wl2[t];
#pragma unroll
    for (int off = 32; off; off >>= 1) p += __shfl_down(p, off);
    if (t == 0) out[g] = 1.f / (1.f + expf(-(p + bl2[0])));
}

extern "C" void kernel_launch(void* const* d_in, const int* in_sizes, int n_in,
                              void* d_out, int out_size, void* d_ws, size_t ws_size,
                              hipStream_t stream) {
    const float* x   = (const float*)d_in[0];
    const int* ei    = (const int*)d_in[1];
    const int* batch = (const int*)d_in[2];
    const float* W1  = (const float*)d_in[3];
    const float* b1  = (const float*)d_in[4];
    const float* W2  = (const float*)d_in[5];
    const float* b2  = (const float*)d_in[6];
    const float* Wl1 = (const float*)d_in[7];
    const float* bl1 = (const float*)d_in[8];
    const float* Wl2 = (const float*)d_in[9];
    const float* bl2 = (const float*)d_in[10];
    float* out = (float*)d_out;

    const int N = in_sizes[2];         // 20000
    const int E = in_sizes[1] / 2;     // 320000
    const int G = 64;
    const int* src = ei;
    const int* dst = ei + E;

    // ---- workspace layout (4-byte elements) ----
    // zeroed region first: deg[N], fillc[N], gsum[G*128], gcnt[G]
    int*   ws_i  = (int*)d_ws;
    int*   deg    = ws_i;                       // N
    int*   fillc  = deg + N;                    // N
    float* gsum   = (float*)(fillc + N);        // G*128
    float* gcnt   = gsum + G * 128;             // G
    size_t zero_elems = (size_t)2 * N + G * 128 + G;
    int*   rowptr = (int*)(gcnt + G);           // N+1
    int*   csr_src= rowptr + N + 4;             // E (pad rowptr to keep 16B align)
    float* dinv   = (float*)(csr_src + E);      // N
    float* h      = dinv + N;                   // N*256
    float* out1   = h    + (size_t)N * 256;     // N*256
    float* t      = out1 + (size_t)N * 256;     // N*128

    hipMemsetAsync(d_ws, 0, zero_elems * sizeof(float), stream);

    // CSR build + norms
    deg_kernel<<<(E + 255) / 256, 256, 0, stream>>>(dst, deg, E);
    dinv_kernel<<<(N + 255) / 256, 256, 0, stream>>>(deg, dinv, N);
    scan_kernel<<<1, 256, 0, stream>>>(deg, rowptr, N);
    fill_kernel<<<(E + 255) / 256, 256, 0, stream>>>(src, dst, rowptr, fillc, csr_src, E);

    // layer 1: h = x @ W1 ; out1 = relu(Ahat h + b1)
    {
        dim3 grid(256 / 64, (N + 63) / 64);
        gemm_tile<<<grid, 256, 0, stream>>>(x, W1, h, N, 256, 256);
        gather256_kernel<<<(N + 3) / 4, 256, 0, stream>>>(h, csr_src, rowptr, dinv, b1, out1, N);
    }
    // layer 2: t = out1 @ W2 ; pooled relu(Ahat t + b2)
    {
        dim3 grid(128 / 64, (N + 63) / 64);
        gemm_tile<<<grid, 256, 0, stream>>>(out1, W2, t, N, 256, 128);
        gather128_pool_kernel<<<(N + 3) / 4, 256, 0, stream>>>(t, csr_src, rowptr, dinv, b2,
                                                               batch, gsum, gcnt, N);
    }
    // head
    head_kernel<<<G, 64, 0, stream>>>(gsum, gcnt, Wl1, bl1, Wl2, bl2, out);
}

// Round 3
// 354.609 us; speedup vs baseline: 4.7597x; 1.2985x over previous
//
#include <hip/hip_runtime.h>
#include <hip/hip_bf16.h>
#include <math.h>

typedef __attribute__((ext_vector_type(8))) short bf16x8;
typedef __attribute__((ext_vector_type(4))) float f32x4;

__device__ __forceinline__ unsigned short f2bf(float f) {
    unsigned int u = __float_as_uint(f);
    unsigned int r = (u + 0x7FFFu + ((u >> 16) & 1u)) >> 16;
    return (unsigned short)r;
}
__device__ __forceinline__ float bf2f(unsigned short h) {
    return __uint_as_float(((unsigned int)h) << 16);
}

// ---------------- degree histogram (int) ----------------
__global__ void deg_kernel(const int* __restrict__ dst, int* __restrict__ deg, int E) {
    int e = blockIdx.x * blockDim.x + threadIdx.x;
    if (e < E) atomicAdd(&deg[dst[e]], 1);
}

__global__ void dinv_kernel(const int* __restrict__ deg, float* __restrict__ dinv, int N) {
    int i = blockIdx.x * blockDim.x + threadIdx.x;
    if (i < N) dinv[i] = rsqrtf((float)deg[i] + 1.0f);   // +1 self-loop
}

// ---------------- exclusive prefix scan of deg -> rowptr (single block) ----------------
__global__ __launch_bounds__(256) void scan_kernel(const int* __restrict__ deg,
                                                   int* __restrict__ rowptr, int N) {
    __shared__ int sums[256];
    int t = threadIdx.x;
    int chunk = (N + 255) / 256;
    int start = t * chunk;
    int end = start + chunk; if (end > N) end = N; if (start > N) start = N;
    int s = 0;
    for (int i = start; i < end; i++) s += deg[i];
    sums[t] = s;
    __syncthreads();
    for (int off = 1; off < 256; off <<= 1) {
        int v = (t >= off) ? sums[t - off] : 0;
        __syncthreads();
        sums[t] += v;
        __syncthreads();
    }
    int run = (t == 0) ? 0 : sums[t - 1];
    for (int i = start; i < end; i++) { rowptr[i] = run; run += deg[i]; }
    if (t == 255) rowptr[N] = run;
}

// ---------------- CSR fill ----------------
__global__ void fill_kernel(const int* __restrict__ src, const int* __restrict__ dst,
                            const int* __restrict__ rowptr, int* __restrict__ fill,
                            int* __restrict__ csr_src, int E) {
    int e = blockIdx.x * blockDim.x + threadIdx.x;
    if (e >= E) return;
    int d = dst[e];
    int pos = rowptr[d] + atomicAdd(&fill[d], 1);
    csr_src[pos] = src[e];
}

// ---------------- graph boundaries from sorted batch ----------------
__global__ void bounds_kernel(const int* __restrict__ batch, int* __restrict__ gstart,
                              int N, int G) {
    int i = blockIdx.x * blockDim.x + threadIdx.x;
    if (i >= N) return;
    int b = batch[i];
    if (i == 0) {
        for (int g = 0; g <= b; g++) gstart[g] = 0;
    } else {
        int bp = batch[i - 1];
        for (int g = bp + 1; g <= b; g++) gstart[g] = i;
    }
    if (i == N - 1) {
        for (int g = b + 1; g <= G; g++) gstart[g] = N;
    }
}

// ---------------- conversions ----------------
__global__ void convert_x_kernel(const float* __restrict__ x, unsigned short* __restrict__ xh,
                                 size_t total4) {
    size_t idx = (size_t)blockIdx.x * blockDim.x + threadIdx.x;
    if (idx >= total4) return;
    float4 v = ((const float4*)x)[idx];
    ushort4 o;
    o.x = f2bf(v.x); o.y = f2bf(v.y); o.z = f2bf(v.z); o.w = f2bf(v.w);
    ((ushort4*)xh)[idx] = o;
}

// W [K][M] fp32 -> Wt hi/lo [M][K] bf16 (transposed, split)
__global__ void convert_w_kernel(const float* __restrict__ W, unsigned short* __restrict__ Wth,
                                 unsigned short* __restrict__ Wtl, int K, int M) {
    int idx = blockIdx.x * blockDim.x + threadIdx.x;
    if (idx >= M * K) return;
    int m = idx / K, k = idx - m * K;
    float w = W[(size_t)k * M + m];
    unsigned short hi = f2bf(w);
    Wth[idx] = hi;
    Wtl[idx] = f2bf(w - bf2f(hi));
}

// ---------------- MFMA GEMM: C[N][M] fp32 = A[N][K]bf16 @ (Bth+Btl)[M][K]bf16^T ----------------
// block = 256 thr (4 waves); block tile 64 rows x 64 cols; wave tile 16 x 64.
__global__ __launch_bounds__(256) void gemm_mfma(const unsigned short* __restrict__ A,
                                                 const unsigned short* __restrict__ Bth,
                                                 const unsigned short* __restrict__ Btl,
                                                 float* __restrict__ C,
                                                 int N, int K, int M) {
    int wave = threadIdx.x >> 6;
    int lane = threadIdx.x & 63;
    int quad = lane >> 4;
    int m16 = lane & 15;
    int r0 = blockIdx.y * 64 + wave * 16;
    int c0 = blockIdx.x * 64;
    int arow = r0 + m16; if (arow >= N) arow = N - 1;   // clamp; OOB rows never stored
    const unsigned short* Ap = A + (size_t)arow * K + quad * 8;

    f32x4 acc[4];
#pragma unroll
    for (int t = 0; t < 4; t++) acc[t] = (f32x4){0.f, 0.f, 0.f, 0.f};

    for (int kb = 0; kb < K; kb += 32) {
        bf16x8 af = *(const bf16x8*)(Ap + kb);
#pragma unroll
        for (int t = 0; t < 4; t++) {
            size_t boff = (size_t)(c0 + t * 16 + m16) * K + kb + quad * 8;
            bf16x8 bh = *(const bf16x8*)(Bth + boff);
            bf16x8 bl = *(const bf16x8*)(Btl + boff);
            acc[t] = __builtin_amdgcn_mfma_f32_16x16x32_bf16(af, bh, acc[t], 0, 0, 0);
            acc[t] = __builtin_amdgcn_mfma_f32_16x16x32_bf16(af, bl, acc[t], 0, 0, 0);
        }
    }
#pragma unroll
    for (int t = 0; t < 4; t++) {
        int col = c0 + t * 16 + m16;
#pragma unroll
        for (int r = 0; r < 4; r++) {
            int row = blockIdx.y * 64 + wave * 16 + quad * 4 + r;
            if (row < N) C[(size_t)row * M + col] = acc[t][r];
        }
    }
}

// ---------------- gather 256 ch: out1 = relu(Ahat h + b1), stored bf16 ----------------
__global__ __launch_bounds__(256) void gather256_kernel(const float* __restrict__ h,
                                                        const int* __restrict__ csr_src,
                                                        const int* __restrict__ rowptr,
                                                        const float* __restrict__ dinv,
                                                        const float* __restrict__ bias,
                                                        unsigned short* __restrict__ out, int N) {
    int node = blockIdx.x * 4 + (threadIdx.x >> 6);
    if (node >= N) return;
    int lane = threadIdx.x & 63;
    int beg = rowptr[node], end = rowptr[node + 1];
    float4 a0 = {0,0,0,0}, a1 = {0,0,0,0}, a2 = {0,0,0,0}, a3 = {0,0,0,0};
    int j = beg;
    for (; j + 3 < end; j += 4) {
        int s0 = csr_src[j], s1 = csr_src[j+1], s2 = csr_src[j+2], s3 = csr_src[j+3];
        float w0 = dinv[s0], w1 = dinv[s1], w2 = dinv[s2], w3 = dinv[s3];
        float4 v0 = ((const float4*)(h + (size_t)s0 * 256))[lane];
        float4 v1 = ((const float4*)(h + (size_t)s1 * 256))[lane];
        float4 v2 = ((const float4*)(h + (size_t)s2 * 256))[lane];
        float4 v3 = ((const float4*)(h + (size_t)s3 * 256))[lane];
        a0.x += v0.x*w0; a0.y += v0.y*w0; a0.z += v0.z*w0; a0.w += v0.w*w0;
        a1.x += v1.x*w1; a1.y += v1.y*w1; a1.z += v1.z*w1; a1.w += v1.w*w1;
        a2.x += v2.x*w2; a2.y += v2.y*w2; a2.z += v2.z*w2; a2.w += v2.w*w2;
        a3.x += v3.x*w3; a3.y += v3.y*w3; a3.z += v3.z*w3; a3.w += v3.w*w3;
    }
    for (; j < end; j++) {
        int s0 = csr_src[j];
        float w0 = dinv[s0];
        float4 v0 = ((const float4*)(h + (size_t)s0 * 256))[lane];
        a0.x += v0.x*w0; a0.y += v0.y*w0; a0.z += v0.z*w0; a0.w += v0.w*w0;
    }
    float dd = dinv[node];
    float4 hv = ((const float4*)(h + (size_t)node * 256))[lane];
    float4 bv = ((const float4*)bias)[lane];
    float rx = fmaxf((a0.x+a1.x+a2.x+a3.x + hv.x*dd) * dd + bv.x, 0.f);
    float ry = fmaxf((a0.y+a1.y+a2.y+a3.y + hv.y*dd) * dd + bv.y, 0.f);
    float rz = fmaxf((a0.z+a1.z+a2.z+a3.z + hv.z*dd) * dd + bv.z, 0.f);
    float rw = fmaxf((a0.w+a1.w+a2.w+a3.w + hv.w*dd) * dd + bv.w, 0.f);
    ushort4 o; o.x = f2bf(rx); o.y = f2bf(ry); o.z = f2bf(rz); o.w = f2bf(rw);
    ((ushort4*)(out + (size_t)node * 256))[lane] = o;
}

// ---------------- gather 128 ch: out2 = relu(Ahat t + b2), fp32 ----------------
__global__ __launch_bounds__(256) void gather128_kernel(const float* __restrict__ t,
                                                        const int* __restrict__ csr_src,
                                                        const int* __restrict__ rowptr,
                                                        const float* __restrict__ dinv,
                                                        const float* __restrict__ bias,
                                                        float* __restrict__ out2, int N) {
    int node = blockIdx.x * 4 + (threadIdx.x >> 6);
    if (node >= N) return;
    int lane = threadIdx.x & 63;
    int beg = rowptr[node], end = rowptr[node + 1];
    float2 a0 = {0,0}, a1 = {0,0}, a2 = {0,0}, a3 = {0,0};
    int j = beg;
    for (; j + 3 < end; j += 4) {
        int s0 = csr_src[j], s1 = csr_src[j+1], s2 = csr_src[j+2], s3 = csr_src[j+3];
        float w0 = dinv[s0], w1 = dinv[s1], w2 = dinv[s2], w3 = dinv[s3];
        float2 v0 = ((const float2*)(t + (size_t)s0 * 128))[lane];
        float2 v1 = ((const float2*)(t + (size_t)s1 * 128))[lane];
        float2 v2 = ((const float2*)(t + (size_t)s2 * 128))[lane];
        float2 v3 = ((const float2*)(t + (size_t)s3 * 128))[lane];
        a0.x += v0.x*w0; a0.y += v0.y*w0;
        a1.x += v1.x*w1; a1.y += v1.y*w1;
        a2.x += v2.x*w2; a2.y += v2.y*w2;
        a3.x += v3.x*w3; a3.y += v3.y*w3;
    }
    for (; j < end; j++) {
        int s0 = csr_src[j];
        float w0 = dinv[s0];
        float2 v0 = ((const float2*)(t + (size_t)s0 * 128))[lane];
        a0.x += v0.x*w0; a0.y += v0.y*w0;
    }
    float dd = dinv[node];
    float2 hv = ((const float2*)(t + (size_t)node * 128))[lane];
    float2 bv = ((const float2*)bias)[lane];
    float2 r;
    r.x = fmaxf((a0.x+a1.x+a2.x+a3.x + hv.x*dd) * dd + bv.x, 0.f);
    r.y = fmaxf((a0.y+a1.y+a2.y+a3.y + hv.y*dd) * dd + bv.y, 0.f);
    ((float2*)(out2 + (size_t)node * 128))[lane] = r;
}

// ---------------- segmented mean pool (batch sorted, no atomics) ----------------
__global__ __launch_bounds__(256) void pool_kernel(const float* __restrict__ out2,
                                                   const int* __restrict__ gstart,
                                                   float* __restrict__ gmean) {
    int g = blockIdx.x;
    int tid = threadIdx.x;
    int c = tid & 127, half = tid >> 7;
    int gs = gstart[g], ge = gstart[g + 1];
    float s = 0.f;
    for (int i = gs + half; i < ge; i += 2) s += out2[(size_t)i * 128 + c];
    __shared__ float red[256];
    red[tid] = s;
    __syncthreads();
    if (tid < 128) {
        float m = red[tid] + red[tid + 128];
        int cnt = ge - gs;
        gmean[g * 128 + tid] = (cnt > 0) ? m / (float)cnt : 0.f;
    }
}

// ---------------- head: FC64+relu, FC1+sigmoid ----------------
__global__ void head_kernel(const float* __restrict__ gmean,
                            const float* __restrict__ Wl1, const float* __restrict__ bl1,
                            const float* __restrict__ Wl2, const float* __restrict__ bl2,
                            float* __restrict__ out) {
    int g = blockIdx.x;
    int t = threadIdx.x;  // 64 threads
    __shared__ float gv[128];
    gv[t]      = gmean[g * 128 + t];
    gv[t + 64] = gmean[g * 128 + 64 + t];
    __syncthreads();
    float acc = bl1[t];
    for (int k = 0; k < 128; k++) acc += gv[k] * Wl1[k * 64 + t];
    acc = fmaxf(acc, 0.f);
    float p = acc * Wl2[t];
#pragma unroll
    for (int off = 32; off; off >>= 1) p += __shfl_down(p, off);
    if (t == 0) out[g] = 1.f / (1.f + expf(-(p + bl2[0])));
}

extern "C" void kernel_launch(void* const* d_in, const int* in_sizes, int n_in,
                              void* d_out, int out_size, void* d_ws, size_t ws_size,
                              hipStream_t stream) {
    const float* x   = (const float*)d_in[0];
    const int* ei    = (const int*)d_in[1];
    const int* batch = (const int*)d_in[2];
    const float* W1  = (const float*)d_in[3];
    const float* b1  = (const float*)d_in[4];
    const float* W2  = (const float*)d_in[5];
    const float* b2  = (const float*)d_in[6];
    const float* Wl1 = (const float*)d_in[7];
    const float* bl1 = (const float*)d_in[8];
    const float* Wl2 = (const float*)d_in[9];
    const float* bl2 = (const float*)d_in[10];
    float* out = (float*)d_out;

    const int N = in_sizes[2];         // 20000
    const int E = in_sizes[1] / 2;     // 320000
    const int G = 64;
    const int* src = ei;
    const int* dst = ei + E;

    // ---- workspace layout (4-byte units, 16B-aligned carve-outs) ----
    char* base = (char*)d_ws;
    size_t off = 0;
    auto carve = [&](size_t bytes) -> char* {
        char* p = base + off;
        off = (off + bytes + 15) & ~(size_t)15;
        return p;
    };
    int*   deg    = (int*)carve((size_t)N * 4);
    int*   fillc  = (int*)carve((size_t)N * 4);          // [deg,fillc] zeroed
    int*   rowptr = (int*)carve((size_t)(N + 1) * 4);
    int*   csr    = (int*)carve((size_t)E * 4);
    float* dinv   = (float*)carve((size_t)N * 4);
    int*   gstart = (int*)carve((size_t)(G + 1) * 4);
    float* gmean  = (float*)carve((size_t)G * 128 * 4);
    unsigned short* w1th = (unsigned short*)carve((size_t)256 * 256 * 2);
    unsigned short* w1tl = (unsigned short*)carve((size_t)256 * 256 * 2);
    unsigned short* w2th = (unsigned short*)carve((size_t)128 * 256 * 2);
    unsigned short* w2tl = (unsigned short*)carve((size_t)128 * 256 * 2);
    unsigned short* xh   = (unsigned short*)carve((size_t)N * 256 * 2);   // aliased by out2 later
    float* h             = (float*)carve((size_t)N * 256 * 4);            // aliased by t later
    unsigned short* o1h  = (unsigned short*)carve((size_t)N * 256 * 2);
    // aliases (lifetime-disjoint):
    float* t    = h;               // t [N][128] fp32 <= h region; h dead after gather256
    float* out2 = (float*)xh;      // out2 [N][128] fp32 == xh region size; xh dead after gemm1

    hipMemsetAsync(d_ws, 0, (size_t)2 * N * 4, stream);   // deg + fillc

    // CSR build + norms + graph bounds
    deg_kernel<<<(E + 255) / 256, 256, 0, stream>>>(dst, deg, E);
    dinv_kernel<<<(N + 255) / 256, 256, 0, stream>>>(deg, dinv, N);
    scan_kernel<<<1, 256, 0, stream>>>(deg, rowptr, N);
    fill_kernel<<<(E + 255) / 256, 256, 0, stream>>>(src, dst, rowptr, fillc, csr, E);
    bounds_kernel<<<(N + 255) / 256, 256, 0, stream>>>(batch, gstart, N, G);

    // weight + input conversion
    convert_w_kernel<<<(256 * 256 + 255) / 256, 256, 0, stream>>>(W1, w1th, w1tl, 256, 256);
    convert_w_kernel<<<(128 * 256 + 255) / 256, 256, 0, stream>>>(W2, w2th, w2tl, 256, 128);
    convert_x_kernel<<<(int)(((size_t)N * 64 + 255) / 256), 256, 0, stream>>>(x, xh, (size_t)N * 64);

    // layer 1: h = x @ W1 (MFMA) ; out1 = relu(Ahat h + b1) -> bf16
    {
        dim3 grid(256 / 64, (N + 63) / 64);
        gemm_mfma<<<grid, 256, 0, stream>>>(xh, w1th, w1tl, h, N, 256, 256);
        gather256_kernel<<<(N + 3) / 4, 256, 0, stream>>>(h, csr, rowptr, dinv, b1, o1h, N);
    }
    // layer 2: t = out1 @ W2 (MFMA) ; out2 = relu(Ahat t + b2)
    {
        dim3 grid(128 / 64, (N + 63) / 64);
        gemm_mfma<<<grid, 256, 0, stream>>>(o1h, w2th, w2tl, t, N, 256, 128);
        gather128_kernel<<<(N + 3) / 4, 256, 0, stream>>>(t, csr, rowptr, dinv, b2, out2, N);
    }
    // pool + head
    pool_kernel<<<G, 256, 0, stream>>>(out2, gstart, gmean);
    head_kernel<<<G, 64, 0, stream>>>(gmean, Wl1, bl1, Wl2, bl2, out);
}

// Round 4
// 285.243 us; speedup vs baseline: 5.9171x; 1.2432x over previous
//
#include <hip/hip_runtime.h>
#include <hip/hip_bf16.h>
#include <math.h>

typedef __attribute__((ext_vector_type(8))) short bf16x8;
typedef __attribute__((ext_vector_type(4))) float f32x4;

__device__ __forceinline__ unsigned short f2bf(float f) {
    unsigned int u = __float_as_uint(f);
    unsigned int r = (u + 0x7FFFu + ((u >> 16) & 1u)) >> 16;
    return (unsigned short)r;
}
__device__ __forceinline__ float bf2f(unsigned short h) {
    return __uint_as_float(((unsigned int)h) << 16);
}

__device__ __forceinline__ void load_lds16(const unsigned short* g, unsigned short* l) {
    __builtin_amdgcn_global_load_lds(
        (const __attribute__((address_space(1))) unsigned int*)g,
        (__attribute__((address_space(3))) unsigned int*)l, 16, 0, 0);
}

// ---------------- degree histogram (int) ----------------
__global__ void deg_kernel(const int* __restrict__ dst, int* __restrict__ deg, int E) {
    int e = blockIdx.x * blockDim.x + threadIdx.x;
    if (e < E) atomicAdd(&deg[dst[e]], 1);
}

// ---------------- exclusive scan of deg -> rowptr, + dinv (single block, 1024 thr) ----------------
__global__ __launch_bounds__(1024) void scan_kernel(const int* __restrict__ deg,
                                                    int* __restrict__ rowptr,
                                                    float* __restrict__ dinv, int N) {
    __shared__ int sums[1024];
    int t = threadIdx.x;
    int chunk = (N + 1023) >> 10;
    int start = t * chunk;
    int end = start + chunk;
    if (start > N) start = N;
    if (end > N) end = N;
    int s = 0;
    for (int i = start; i < end; i++) s += deg[i];
    sums[t] = s;
    __syncthreads();
    for (int off = 1; off < 1024; off <<= 1) {
        int v = (t >= off) ? sums[t - off] : 0;
        __syncthreads();
        sums[t] += v;
        __syncthreads();
    }
    int run = (t == 0) ? 0 : sums[t - 1];
    for (int i = start; i < end; i++) {
        int d = deg[i];
        rowptr[i] = run; run += d;
        dinv[i] = rsqrtf((float)d + 1.0f);
    }
    if (t == 1023) rowptr[N] = run;
}

// ---------------- CSR fill ----------------
__global__ void fill_kernel(const int* __restrict__ src, const int* __restrict__ dst,
                            const int* __restrict__ rowptr, int* __restrict__ fill,
                            int* __restrict__ csr_src, int E) {
    int e = blockIdx.x * blockDim.x + threadIdx.x;
    if (e >= E) return;
    int d = dst[e];
    int pos = rowptr[d] + atomicAdd(&fill[d], 1);
    csr_src[pos] = src[e];
}

// ---------------- graph boundaries from sorted batch ----------------
__global__ void bounds_kernel(const int* __restrict__ batch, int* __restrict__ gstart,
                              int N, int G) {
    int i = blockIdx.x * blockDim.x + threadIdx.x;
    if (i >= N) return;
    int b = batch[i];
    if (i == 0) {
        for (int g = 0; g <= b; g++) gstart[g] = 0;
    } else {
        int bp = batch[i - 1];
        for (int g = bp + 1; g <= b; g++) gstart[g] = i;
    }
    if (i == N - 1) {
        for (int g = b + 1; g <= G; g++) gstart[g] = N;
    }
}

// ---------------- conversions ----------------
__global__ void convert_x_kernel(const float* __restrict__ x, unsigned short* __restrict__ xh,
                                 size_t total4) {
    size_t idx = (size_t)blockIdx.x * blockDim.x + threadIdx.x;
    if (idx >= total4) return;
    float4 v = ((const float4*)x)[idx];
    ushort4 o;
    o.x = f2bf(v.x); o.y = f2bf(v.y); o.z = f2bf(v.z); o.w = f2bf(v.w);
    ((ushort4*)xh)[idx] = o;
}

// W [K][M] fp32 -> Wt hi/lo [M][K] bf16 (transposed, split)
__global__ void convert_w_kernel(const float* __restrict__ W, unsigned short* __restrict__ Wth,
                                 unsigned short* __restrict__ Wtl, int K, int M) {
    int idx = blockIdx.x * blockDim.x + threadIdx.x;
    if (idx >= M * K) return;
    int m = idx / K, k = idx - m * K;
    float w = W[(size_t)k * M + m];
    unsigned short hi = f2bf(w);
    Wth[idx] = hi;
    Wtl[idx] = f2bf(w - bf2f(hi));
}

// ---------------- MFMA GEMM with LDS staging ----------------
// C[N][M] bf16 = A[N][K]bf16 @ (Bth+Btl)[M][K]^T.  Block: 256 thr, tile 128 rows x 64 cols,
// BK=32.  Wave w: rows w*32..w*32+31 (2 rowgroups), all 4 col-tiles.
__global__ __launch_bounds__(256) void gemm_mfma(const unsigned short* __restrict__ A,
                                                 const unsigned short* __restrict__ Bth,
                                                 const unsigned short* __restrict__ Btl,
                                                 unsigned short* __restrict__ C,
                                                 int N, int K, int M) {
    __shared__ unsigned short As[128 * 32];
    __shared__ unsigned short Bhs[64 * 32];
    __shared__ unsigned short Bls[64 * 32];
    int tid = threadIdx.x;
    int wave = tid >> 6, lane = tid & 63;
    int quad = lane >> 4, m16 = lane & 15;
    int r0 = blockIdx.y * 128, c0 = blockIdx.x * 64;

    // staging lane roles: 4 lanes per row (16B each), 16 rows per wave-instr
    int srow = lane >> 2;          // 0..15
    int skoff = (lane & 3) * 8;    // element offset within BK

    f32x4 acc[2][4];
#pragma unroll
    for (int rg = 0; rg < 2; rg++)
#pragma unroll
        for (int ct = 0; ct < 4; ct++) acc[rg][ct] = (f32x4){0.f, 0.f, 0.f, 0.f};

    for (int kb = 0; kb < K; kb += 32) {
        // stage A: wave w covers block-rows w*32 + i*16 + srow
#pragma unroll
        for (int i = 0; i < 2; i++) {
            int brow = wave * 32 + i * 16 + srow;
            int grow = r0 + brow; if (grow >= N) grow = N - 1;
            load_lds16(A + (size_t)grow * K + kb + skoff, As + (wave * 32 + i * 16) * 32);
        }
        // stage B hi/lo: wave w covers cols w*16 + srow
        {
            int bcol = wave * 16 + srow;
            size_t goff = (size_t)(c0 + bcol) * K + kb + skoff;
            load_lds16(Bth + goff, Bhs + (wave * 16) * 32);
            load_lds16(Btl + goff, Bls + (wave * 16) * 32);
        }
        __syncthreads();
        bf16x8 af[2], bh[4], bl[4];
#pragma unroll
        for (int rg = 0; rg < 2; rg++)
            af[rg] = *(const bf16x8*)(As + (wave * 32 + rg * 16 + m16) * 32 + quad * 8);
#pragma unroll
        for (int ct = 0; ct < 4; ct++) {
            bh[ct] = *(const bf16x8*)(Bhs + (ct * 16 + m16) * 32 + quad * 8);
            bl[ct] = *(const bf16x8*)(Bls + (ct * 16 + m16) * 32 + quad * 8);
        }
#pragma unroll
        for (int rg = 0; rg < 2; rg++)
#pragma unroll
            for (int ct = 0; ct < 4; ct++) {
                acc[rg][ct] = __builtin_amdgcn_mfma_f32_16x16x32_bf16(af[rg], bh[ct], acc[rg][ct], 0, 0, 0);
                acc[rg][ct] = __builtin_amdgcn_mfma_f32_16x16x32_bf16(af[rg], bl[ct], acc[rg][ct], 0, 0, 0);
            }
        __syncthreads();
    }
#pragma unroll
    for (int rg = 0; rg < 2; rg++) {
#pragma unroll
        for (int ct = 0; ct < 4; ct++) {
            int col = c0 + ct * 16 + m16;
#pragma unroll
            for (int r = 0; r < 4; r++) {
                int row = r0 + wave * 32 + rg * 16 + quad * 4 + r;
                if (row < N) C[(size_t)row * M + col] = f2bf(acc[rg][ct][r]);
            }
        }
    }
}

// ---------------- gather 256 ch (bf16 in): out1 = relu(Ahat h + b1) -> bf16 ----------------
__global__ __launch_bounds__(256) void gather256_kernel(const unsigned short* __restrict__ h,
                                                        const int* __restrict__ csr_src,
                                                        const int* __restrict__ rowptr,
                                                        const float* __restrict__ dinv,
                                                        const float* __restrict__ bias,
                                                        unsigned short* __restrict__ out, int N) {
    int node = blockIdx.x * 4 + (threadIdx.x >> 6);
    if (node >= N) return;
    int lane = threadIdx.x & 63;
    int beg = rowptr[node], end = rowptr[node + 1];
    float4 a0 = {0,0,0,0}, a1 = {0,0,0,0}, a2 = {0,0,0,0}, a3 = {0,0,0,0};
    int j = beg;
    for (; j + 3 < end; j += 4) {
        int s0 = csr_src[j], s1 = csr_src[j+1], s2 = csr_src[j+2], s3 = csr_src[j+3];
        float w0 = dinv[s0], w1 = dinv[s1], w2 = dinv[s2], w3 = dinv[s3];
        ushort4 v0 = ((const ushort4*)(h + (size_t)s0 * 256))[lane];
        ushort4 v1 = ((const ushort4*)(h + (size_t)s1 * 256))[lane];
        ushort4 v2 = ((const ushort4*)(h + (size_t)s2 * 256))[lane];
        ushort4 v3 = ((const ushort4*)(h + (size_t)s3 * 256))[lane];
        a0.x += bf2f(v0.x)*w0; a0.y += bf2f(v0.y)*w0; a0.z += bf2f(v0.z)*w0; a0.w += bf2f(v0.w)*w0;
        a1.x += bf2f(v1.x)*w1; a1.y += bf2f(v1.y)*w1; a1.z += bf2f(v1.z)*w1; a1.w += bf2f(v1.w)*w1;
        a2.x += bf2f(v2.x)*w2; a2.y += bf2f(v2.y)*w2; a2.z += bf2f(v2.z)*w2; a2.w += bf2f(v2.w)*w2;
        a3.x += bf2f(v3.x)*w3; a3.y += bf2f(v3.y)*w3; a3.z += bf2f(v3.z)*w3; a3.w += bf2f(v3.w)*w3;
    }
    for (; j < end; j++) {
        int s0 = csr_src[j];
        float w0 = dinv[s0];
        ushort4 v0 = ((const ushort4*)(h + (size_t)s0 * 256))[lane];
        a0.x += bf2f(v0.x)*w0; a0.y += bf2f(v0.y)*w0; a0.z += bf2f(v0.z)*w0; a0.w += bf2f(v0.w)*w0;
    }
    float dd = dinv[node];
    ushort4 hv = ((const ushort4*)(h + (size_t)node * 256))[lane];
    float4 bv = ((const float4*)bias)[lane];
    float rx = fmaxf((a0.x+a1.x+a2.x+a3.x + bf2f(hv.x)*dd) * dd + bv.x, 0.f);
    float ry = fmaxf((a0.y+a1.y+a2.y+a3.y + bf2f(hv.y)*dd) * dd + bv.y, 0.f);
    float rz = fmaxf((a0.z+a1.z+a2.z+a3.z + bf2f(hv.z)*dd) * dd + bv.z, 0.f);
    float rw = fmaxf((a0.w+a1.w+a2.w+a3.w + bf2f(hv.w)*dd) * dd + bv.w, 0.f);
    ushort4 o; o.x = f2bf(rx); o.y = f2bf(ry); o.z = f2bf(rz); o.w = f2bf(rw);
    ((ushort4*)(out + (size_t)node * 256))[lane] = o;
}

// ---------------- gather 128 ch (bf16 in): out2 = relu(Ahat t + b2) fp32 ----------------
__global__ __launch_bounds__(256) void gather128_kernel(const unsigned short* __restrict__ t,
                                                        const int* __restrict__ csr_src,
                                                        const int* __restrict__ rowptr,
                                                        const float* __restrict__ dinv,
                                                        const float* __restrict__ bias,
                                                        float* __restrict__ out2, int N) {
    int node = blockIdx.x * 4 + (threadIdx.x >> 6);
    if (node >= N) return;
    int lane = threadIdx.x & 63;
    int beg = rowptr[node], end = rowptr[node + 1];
    float2 a0 = {0,0}, a1 = {0,0}, a2 = {0,0}, a3 = {0,0};
    int j = beg;
    for (; j + 3 < end; j += 4) {
        int s0 = csr_src[j], s1 = csr_src[j+1], s2 = csr_src[j+2], s3 = csr_src[j+3];
        float w0 = dinv[s0], w1 = dinv[s1], w2 = dinv[s2], w3 = dinv[s3];
        ushort2 v0 = ((const ushort2*)(t + (size_t)s0 * 128))[lane];
        ushort2 v1 = ((const ushort2*)(t + (size_t)s1 * 128))[lane];
        ushort2 v2 = ((const ushort2*)(t + (size_t)s2 * 128))[lane];
        ushort2 v3 = ((const ushort2*)(t + (size_t)s3 * 128))[lane];
        a0.x += bf2f(v0.x)*w0; a0.y += bf2f(v0.y)*w0;
        a1.x += bf2f(v1.x)*w1; a1.y += bf2f(v1.y)*w1;
        a2.x += bf2f(v2.x)*w2; a2.y += bf2f(v2.y)*w2;
        a3.x += bf2f(v3.x)*w3; a3.y += bf2f(v3.y)*w3;
    }
    for (; j < end; j++) {
        int s0 = csr_src[j];
        float w0 = dinv[s0];
        ushort2 v0 = ((const ushort2*)(t + (size_t)s0 * 128))[lane];
        a0.x += bf2f(v0.x)*w0; a0.y += bf2f(v0.y)*w0;
    }
    float dd = dinv[node];
    ushort2 hv = ((const ushort2*)(t + (size_t)node * 128))[lane];
    float2 bv = ((const float2*)bias)[lane];
    float2 r;
    r.x = fmaxf((a0.x+a1.x+a2.x+a3.x + bf2f(hv.x)*dd) * dd + bv.x, 0.f);
    r.y = fmaxf((a0.y+a1.y+a2.y+a3.y + bf2f(hv.y)*dd) * dd + bv.y, 0.f);
    ((float2*)(out2 + (size_t)node * 128))[lane] = r;
}

// ---------------- segmented mean pool ----------------
__global__ __launch_bounds__(256) void pool_kernel(const float* __restrict__ out2,
                                                   const int* __restrict__ gstart,
                                                   float* __restrict__ gmean) {
    int g = blockIdx.x;
    int tid = threadIdx.x;
    int c = tid & 127, half = tid >> 7;
    int gs = gstart[g], ge = gstart[g + 1];
    float s = 0.f;
    for (int i = gs + half; i < ge; i += 2) s += out2[(size_t)i * 128 + c];
    __shared__ float red[256];
    red[tid] = s;
    __syncthreads();
    if (tid < 128) {
        float m = red[tid] + red[tid + 128];
        int cnt = ge - gs;
        gmean[g * 128 + tid] = (cnt > 0) ? m / (float)cnt : 0.f;
    }
}

// ---------------- head ----------------
__global__ void head_kernel(const float* __restrict__ gmean,
                            const float* __restrict__ Wl1, const float* __restrict__ bl1,
                            const float* __restrict__ Wl2, const float* __restrict__ bl2,
                            float* __restrict__ out) {
    int g = blockIdx.x;
    int t = threadIdx.x;  // 64 threads
    __shared__ float gv[128];
    gv[t]      = gmean[g * 128 + t];
    gv[t + 64] = gmean[g * 128 + 64 + t];
    __syncthreads();
    float acc = bl1[t];
    for (int k = 0; k < 128; k++) acc += gv[k] * Wl1[k * 64 + t];
    acc = fmaxf(acc, 0.f);
    float p = acc * Wl2[t];
#pragma unroll
    for (int off = 32; off; off >>= 1) p += __shfl_down(p, off);
    if (t == 0) out[g] = 1.f / (1.f + expf(-(p + bl2[0])));
}

extern "C" void kernel_launch(void* const* d_in, const int* in_sizes, int n_in,
                              void* d_out, int out_size, void* d_ws, size_t ws_size,
                              hipStream_t stream) {
    const float* x   = (const float*)d_in[0];
    const int* ei    = (const int*)d_in[1];
    const int* batch = (const int*)d_in[2];
    const float* W1  = (const float*)d_in[3];
    const float* b1  = (const float*)d_in[4];
    const float* W2  = (const float*)d_in[5];
    const float* b2  = (const float*)d_in[6];
    const float* Wl1 = (const float*)d_in[7];
    const float* bl1 = (const float*)d_in[8];
    const float* Wl2 = (const float*)d_in[9];
    const float* bl2 = (const float*)d_in[10];
    float* out = (float*)d_out;

    const int N = in_sizes[2];         // 20000
    const int E = in_sizes[1] / 2;     // 320000
    const int G = 64;
    const int* src = ei;
    const int* dst = ei + E;

    // ---- workspace carve ----
    char* base = (char*)d_ws;
    size_t off = 0;
    auto carve = [&](size_t bytes) -> char* {
        char* p = base + off;
        off = (off + bytes + 15) & ~(size_t)15;
        return p;
    };
    int*   deg    = (int*)carve((size_t)N * 4);
    int*   fillc  = (int*)carve((size_t)N * 4);          // [deg,fillc] zeroed
    int*   rowptr = (int*)carve((size_t)(N + 1) * 4);
    int*   csr    = (int*)carve((size_t)E * 4);
    float* dinv   = (float*)carve((size_t)N * 4);
    int*   gstart = (int*)carve((size_t)(G + 1) * 4);
    float* gmean  = (float*)carve((size_t)G * 128 * 4);
    unsigned short* w1th = (unsigned short*)carve((size_t)256 * 256 * 2);
    unsigned short* w1tl = (unsigned short*)carve((size_t)256 * 256 * 2);
    unsigned short* w2th = (unsigned short*)carve((size_t)128 * 256 * 2);
    unsigned short* w2tl = (unsigned short*)carve((size_t)128 * 256 * 2);
    unsigned short* xh   = (unsigned short*)carve((size_t)N * 256 * 2);  // later: out2 fp32? no — out2 overlays xh
    unsigned short* h    = (unsigned short*)carve((size_t)N * 256 * 2);  // later: t
    unsigned short* o1h  = (unsigned short*)carve((size_t)N * 256 * 2);
    // lifetime-disjoint aliases:
    unsigned short* t = h;             // t [N][128] bf16 <= h region; h dead after gather256
    float* out2 = (float*)xh;          // out2 [N][128] fp32 (10.24MB) == xh region; xh dead after gemm1

    hipMemsetAsync(d_ws, 0, (size_t)2 * N * 4, stream);   // deg + fillc

    // CSR + norms + bounds
    deg_kernel<<<(E + 255) / 256, 256, 0, stream>>>(dst, deg, E);
    scan_kernel<<<1, 1024, 0, stream>>>(deg, rowptr, dinv, N);
    fill_kernel<<<(E + 255) / 256, 256, 0, stream>>>(src, dst, rowptr, fillc, csr, E);
    bounds_kernel<<<(N + 255) / 256, 256, 0, stream>>>(batch, gstart, N, G);

    // conversions
    convert_w_kernel<<<(256 * 256 + 255) / 256, 256, 0, stream>>>(W1, w1th, w1tl, 256, 256);
    convert_w_kernel<<<(128 * 256 + 255) / 256, 256, 0, stream>>>(W2, w2th, w2tl, 256, 128);
    convert_x_kernel<<<(int)(((size_t)N * 64 + 255) / 256), 256, 0, stream>>>(x, xh, (size_t)N * 64);

    // layer 1: h = x @ W1 (bf16 out) ; out1 = relu(Ahat h + b1) -> bf16
    {
        dim3 grid(256 / 64, (N + 127) / 128);
        gemm_mfma<<<grid, 256, 0, stream>>>(xh, w1th, w1tl, h, N, 256, 256);
        gather256_kernel<<<(N + 3) / 4, 256, 0, stream>>>(h, csr, rowptr, dinv, b1, o1h, N);
    }
    // layer 2: t = out1 @ W2 (bf16 out) ; out2 = relu(Ahat t + b2) fp32
    {
        dim3 grid(128 / 64, (N + 127) / 128);
        gemm_mfma<<<grid, 256, 0, stream>>>(o1h, w2th, w2tl, t, N, 256, 128);
        gather128_kernel<<<(N + 3) / 4, 256, 0, stream>>>(t, csr, rowptr, dinv, b2, out2, N);
    }
    // pool + head
    pool_kernel<<<G, 256, 0, stream>>>(out2, gstart, gmean);
    head_kernel<<<G, 64, 0, stream>>>(gmean, Wl1, bl1, Wl2, bl2, out);
}

// Round 5
// 239.762 us; speedup vs baseline: 7.0395x; 1.1897x over previous
//
#include <hip/hip_runtime.h>
#include <hip/hip_bf16.h>
#include <math.h>

typedef __attribute__((ext_vector_type(8))) short bf16x8;
typedef __attribute__((ext_vector_type(4))) short bf16x4;
typedef __attribute__((ext_vector_type(4))) float f32x4;

__device__ __forceinline__ unsigned short f2bf(float f) {
    unsigned int u = __float_as_uint(f);
    unsigned int r = (u + 0x7FFFu + ((u >> 16) & 1u)) >> 16;
    return (unsigned short)r;
}
__device__ __forceinline__ float bf2f(unsigned short h) {
    return __uint_as_float(((unsigned int)h) << 16);
}
__device__ __forceinline__ float bfe(short s) {   // bf16 element -> float
    return __uint_as_float(((unsigned int)(unsigned short)s) << 16);
}

__device__ __forceinline__ void load_lds16(const unsigned short* g, unsigned short* l) {
    __builtin_amdgcn_global_load_lds(
        (const __attribute__((address_space(1))) unsigned int*)g,
        (__attribute__((address_space(3))) unsigned int*)l, 16, 0, 0);
}

// ================= fused prep: convert_x | bounds | deg | convert_w =================
// block ranges: [0,CXB) convert_x ; [CXB,CXB+BNB) bounds ; then deg ; then convert_w
__global__ __launch_bounds__(256) void prep_kernel(const float* __restrict__ x,
                                                   unsigned short* __restrict__ xh,
                                                   const int* __restrict__ batch,
                                                   int* __restrict__ gstart,
                                                   const int* __restrict__ dst,
                                                   int* __restrict__ deg,
                                                   const float* __restrict__ W1,
                                                   unsigned short* __restrict__ w1th,
                                                   unsigned short* __restrict__ w1tl,
                                                   const float* __restrict__ W2,
                                                   unsigned short* __restrict__ w2th,
                                                   unsigned short* __restrict__ w2tl,
                                                   int N, int E, int G,
                                                   int CXB, int BNB, int DGB) {
    int b = blockIdx.x;
    int tid = threadIdx.x;
    if (b < CXB) {
        size_t idx = (size_t)b * 256 + tid;          // float4 units
        size_t total4 = (size_t)N * 64;
        if (idx < total4) {
            float4 v = ((const float4*)x)[idx];
            ushort4 o;
            o.x = f2bf(v.x); o.y = f2bf(v.y); o.z = f2bf(v.z); o.w = f2bf(v.w);
            ((ushort4*)xh)[idx] = o;
        }
        return;
    }
    b -= CXB;
    if (b < BNB) {
        int i = b * 256 + tid;
        if (i >= N) return;
        int bb = batch[i];
        if (i == 0) { for (int g = 0; g <= bb; g++) gstart[g] = 0; }
        else { int bp = batch[i - 1]; for (int g = bp + 1; g <= bb; g++) gstart[g] = i; }
        if (i == N - 1) { for (int g = bb + 1; g <= G; g++) gstart[g] = N; }
        return;
    }
    b -= BNB;
    if (b < DGB) {
        int e = b * 256 + tid;
        if (e < E) atomicAdd(&deg[dst[e]], 1);
        return;
    }
    b -= DGB;
    {
        int idx = b * 256 + tid;                     // W1: 256*256, then W2: 256*128
        if (idx < 256 * 256) {
            int m = idx >> 8, k = idx & 255;
            float w = W1[(size_t)k * 256 + m];
            unsigned short hi = f2bf(w);
            w1th[idx] = hi;
            w1tl[idx] = f2bf(w - bf2f(hi));
        } else if (idx < 256 * 256 + 128 * 256) {
            int j = idx - 256 * 256;
            int m = j >> 8, k = j & 255;
            float w = W2[(size_t)k * 128 + m];
            unsigned short hi = f2bf(w);
            w2th[j] = hi;
            w2tl[j] = f2bf(w - bf2f(hi));
        }
    }
}

// ---------------- exclusive scan of deg -> rowptr, + dinv (single block, 1024 thr) ----------------
__global__ __launch_bounds__(1024) void scan_kernel(const int* __restrict__ deg,
                                                    int* __restrict__ rowptr,
                                                    float* __restrict__ dinv, int N) {
    __shared__ int sums[1024];
    int t = threadIdx.x;
    int chunk = (N + 1023) >> 10;
    int start = t * chunk;
    int end = start + chunk;
    if (start > N) start = N;
    if (end > N) end = N;
    int s = 0;
    for (int i = start; i < end; i++) s += deg[i];
    sums[t] = s;
    __syncthreads();
    for (int off = 1; off < 1024; off <<= 1) {
        int v = (t >= off) ? sums[t - off] : 0;
        __syncthreads();
        sums[t] += v;
        __syncthreads();
    }
    int run = (t == 0) ? 0 : sums[t - 1];
    for (int i = start; i < end; i++) {
        int d = deg[i];
        rowptr[i] = run; run += d;
        dinv[i] = rsqrtf((float)d + 1.0f);
    }
    if (t == 1023) rowptr[N] = run;
}

// ---------------- CSR fill ----------------
__global__ void fill_kernel(const int* __restrict__ src, const int* __restrict__ dst,
                            const int* __restrict__ rowptr, int* __restrict__ fill,
                            int* __restrict__ csr_src, int E) {
    int e = blockIdx.x * blockDim.x + threadIdx.x;
    if (e >= E) return;
    int d = dst[e];
    int pos = rowptr[d] + atomicAdd(&fill[d], 1);
    csr_src[pos] = src[e];
}

// ---------------- MFMA GEMM with LDS staging (unchanged from R4) ----------------
__global__ __launch_bounds__(256) void gemm_mfma(const unsigned short* __restrict__ A,
                                                 const unsigned short* __restrict__ Bth,
                                                 const unsigned short* __restrict__ Btl,
                                                 unsigned short* __restrict__ C,
                                                 int N, int K, int M) {
    __shared__ unsigned short As[128 * 32];
    __shared__ unsigned short Bhs[64 * 32];
    __shared__ unsigned short Bls[64 * 32];
    int tid = threadIdx.x;
    int wave = tid >> 6, lane = tid & 63;
    int quad = lane >> 4, m16 = lane & 15;
    int r0 = blockIdx.y * 128, c0 = blockIdx.x * 64;
    int srow = lane >> 2;
    int skoff = (lane & 3) * 8;

    f32x4 acc[2][4];
#pragma unroll
    for (int rg = 0; rg < 2; rg++)
#pragma unroll
        for (int ct = 0; ct < 4; ct++) acc[rg][ct] = (f32x4){0.f, 0.f, 0.f, 0.f};

    for (int kb = 0; kb < K; kb += 32) {
#pragma unroll
        for (int i = 0; i < 2; i++) {
            int brow = wave * 32 + i * 16 + srow;
            int grow = r0 + brow; if (grow >= N) grow = N - 1;
            load_lds16(A + (size_t)grow * K + kb + skoff, As + (wave * 32 + i * 16) * 32);
        }
        {
            int bcol = wave * 16 + srow;
            size_t goff = (size_t)(c0 + bcol) * K + kb + skoff;
            load_lds16(Bth + goff, Bhs + (wave * 16) * 32);
            load_lds16(Btl + goff, Bls + (wave * 16) * 32);
        }
        __syncthreads();
        bf16x8 af[2], bh[4], bl[4];
#pragma unroll
        for (int rg = 0; rg < 2; rg++)
            af[rg] = *(const bf16x8*)(As + (wave * 32 + rg * 16 + m16) * 32 + quad * 8);
#pragma unroll
        for (int ct = 0; ct < 4; ct++) {
            bh[ct] = *(const bf16x8*)(Bhs + (ct * 16 + m16) * 32 + quad * 8);
            bl[ct] = *(const bf16x8*)(Bls + (ct * 16 + m16) * 32 + quad * 8);
        }
#pragma unroll
        for (int rg = 0; rg < 2; rg++)
#pragma unroll
            for (int ct = 0; ct < 4; ct++) {
                acc[rg][ct] = __builtin_amdgcn_mfma_f32_16x16x32_bf16(af[rg], bh[ct], acc[rg][ct], 0, 0, 0);
                acc[rg][ct] = __builtin_amdgcn_mfma_f32_16x16x32_bf16(af[rg], bl[ct], acc[rg][ct], 0, 0, 0);
            }
        __syncthreads();
    }
#pragma unroll
    for (int rg = 0; rg < 2; rg++) {
#pragma unroll
        for (int ct = 0; ct < 4; ct++) {
            int col = c0 + ct * 16 + m16;
#pragma unroll
            for (int r = 0; r < 4; r++) {
                int row = r0 + wave * 32 + rg * 16 + quad * 4 + r;
                if (row < N) C[(size_t)row * M + col] = f2bf(acc[rg][ct][r]);
            }
        }
    }
}

// ---------------- gather 256 ch: 2 neighbors per wave-instr (16B/lane) ----------------
// wave = 1 node; half h (lane>>5) covers neighbor j+h; lane hl covers ch hl*8..hl*8+7
__global__ __launch_bounds__(256) void gather256_kernel(const unsigned short* __restrict__ h,
                                                        const int* __restrict__ csr_src,
                                                        const int* __restrict__ rowptr,
                                                        const float* __restrict__ dinv,
                                                        const float* __restrict__ bias,
                                                        unsigned short* __restrict__ out, int N) {
    int node = blockIdx.x * 4 + (threadIdx.x >> 6);
    if (node >= N) return;
    int lane = threadIdx.x & 63;
    int half = lane >> 5, hl = lane & 31;
    int beg = rowptr[node], end = rowptr[node + 1];
    float a[8] = {0, 0, 0, 0, 0, 0, 0, 0};
    int j = beg;
    for (; j + 3 < end; j += 4) {
        int s0 = csr_src[j + half], s1 = csr_src[j + 2 + half];
        float w0 = dinv[s0], w1 = dinv[s1];
        bf16x8 v0 = *(const bf16x8*)(h + (size_t)s0 * 256 + hl * 8);
        bf16x8 v1 = *(const bf16x8*)(h + (size_t)s1 * 256 + hl * 8);
#pragma unroll
        for (int i = 0; i < 8; i++) a[i] += bfe(v0[i]) * w0 + bfe(v1[i]) * w1;
    }
    if (j + 1 < end) {
        int s0 = csr_src[j + half];
        float w0 = dinv[s0];
        bf16x8 v0 = *(const bf16x8*)(h + (size_t)s0 * 256 + hl * 8);
#pragma unroll
        for (int i = 0; i < 8; i++) a[i] += bfe(v0[i]) * w0;
        j += 2;
    }
    if (j < end && half == 0) {
        int s0 = csr_src[j];
        float w0 = dinv[s0];
        bf16x8 v0 = *(const bf16x8*)(h + (size_t)s0 * 256 + hl * 8);
#pragma unroll
        for (int i = 0; i < 8; i++) a[i] += bfe(v0[i]) * w0;
    }
#pragma unroll
    for (int i = 0; i < 8; i++) a[i] += __shfl_down(a[i], 32);
    if (half == 0) {
        float dd = dinv[node];
        bf16x8 hv = *(const bf16x8*)(h + (size_t)node * 256 + hl * 8);
        float4 bv0 = ((const float4*)bias)[hl * 2];
        float4 bv1 = ((const float4*)bias)[hl * 2 + 1];
        float bvf[8] = {bv0.x, bv0.y, bv0.z, bv0.w, bv1.x, bv1.y, bv1.z, bv1.w};
        bf16x8 o;
#pragma unroll
        for (int i = 0; i < 8; i++)
            o[i] = (short)f2bf(fmaxf((a[i] + bfe(hv[i]) * dd) * dd + bvf[i], 0.f));
        ((bf16x8*)(out + (size_t)node * 256))[hl] = o;
    }
}

// ---------------- gather 128 ch: 2 neighbors per wave-instr (8B/lane) ----------------
__global__ __launch_bounds__(256) void gather128_kernel(const unsigned short* __restrict__ t,
                                                        const int* __restrict__ csr_src,
                                                        const int* __restrict__ rowptr,
                                                        const float* __restrict__ dinv,
                                                        const float* __restrict__ bias,
                                                        float* __restrict__ out2, int N) {
    int node = blockIdx.x * 4 + (threadIdx.x >> 6);
    if (node >= N) return;
    int lane = threadIdx.x & 63;
    int half = lane >> 5, hl = lane & 31;
    int beg = rowptr[node], end = rowptr[node + 1];
    float a[4] = {0, 0, 0, 0};
    int j = beg;
    for (; j + 3 < end; j += 4) {
        int s0 = csr_src[j + half], s1 = csr_src[j + 2 + half];
        float w0 = dinv[s0], w1 = dinv[s1];
        bf16x4 v0 = *(const bf16x4*)(t + (size_t)s0 * 128 + hl * 4);
        bf16x4 v1 = *(const bf16x4*)(t + (size_t)s1 * 128 + hl * 4);
#pragma unroll
        for (int i = 0; i < 4; i++) a[i] += bfe(v0[i]) * w0 + bfe(v1[i]) * w1;
    }
    if (j + 1 < end) {
        int s0 = csr_src[j + half];
        float w0 = dinv[s0];
        bf16x4 v0 = *(const bf16x4*)(t + (size_t)s0 * 128 + hl * 4);
#pragma unroll
        for (int i = 0; i < 4; i++) a[i] += bfe(v0[i]) * w0;
        j += 2;
    }
    if (j < end && half == 0) {
        int s0 = csr_src[j];
        float w0 = dinv[s0];
        bf16x4 v0 = *(const bf16x4*)(t + (size_t)s0 * 128 + hl * 4);
#pragma unroll
        for (int i = 0; i < 4; i++) a[i] += bfe(v0[i]) * w0;
    }
#pragma unroll
    for (int i = 0; i < 4; i++) a[i] += __shfl_down(a[i], 32);
    if (half == 0) {
        float dd = dinv[node];
        bf16x4 hv = *(const bf16x4*)(t + (size_t)node * 128 + hl * 4);
        float4 bv = ((const float4*)bias)[hl];
        float4 r;
        r.x = fmaxf((a[0] + bfe(hv[0]) * dd) * dd + bv.x, 0.f);
        r.y = fmaxf((a[1] + bfe(hv[1]) * dd) * dd + bv.y, 0.f);
        r.z = fmaxf((a[2] + bfe(hv[2]) * dd) * dd + bv.z, 0.f);
        r.w = fmaxf((a[3] + bfe(hv[3]) * dd) * dd + bv.w, 0.f);
        ((float4*)(out2 + (size_t)node * 128))[hl] = r;
    }
}

// ---------------- parallel segmented mean pool: 8 slices/graph + atomic flush ----------------
__global__ __launch_bounds__(256) void pool_kernel(const float* __restrict__ out2,
                                                   const int* __restrict__ gstart,
                                                   float* __restrict__ gsum) {
    int g = blockIdx.x >> 3, slice = blockIdx.x & 7;
    int tid = threadIdx.x;
    int c = tid & 127, half = tid >> 7;
    int gs = gstart[g], ge = gstart[g + 1];
    float s = 0.f;
    for (int i = gs + slice * 2 + half; i < ge; i += 16) s += out2[(size_t)i * 128 + c];
    __shared__ float red[256];
    red[tid] = s;
    __syncthreads();
    if (tid < 128) {
        float m = red[tid] + red[tid + 128];
        if (m != 0.f) atomicAdd(&gsum[g * 128 + tid], m);
    }
}

// ---------------- head: mean divide, FC64+relu, FC1+sigmoid ----------------
__global__ void head_kernel(const float* __restrict__ gsum, const int* __restrict__ gstart,
                            const float* __restrict__ Wl1, const float* __restrict__ bl1,
                            const float* __restrict__ Wl2, const float* __restrict__ bl2,
                            float* __restrict__ out) {
    int g = blockIdx.x;
    int t = threadIdx.x;  // 64 threads
    __shared__ float gv[128];
    float cnt = fmaxf((float)(gstart[g + 1] - gstart[g]), 1.0f);
    gv[t]      = gsum[g * 128 + t] / cnt;
    gv[t + 64] = gsum[g * 128 + 64 + t] / cnt;
    __syncthreads();
    float acc = bl1[t];
    for (int k = 0; k < 128; k++) acc += gv[k] * Wl1[k * 64 + t];
    acc = fmaxf(acc, 0.f);
    float p = acc * Wl2[t];
#pragma unroll
    for (int off = 32; off; off >>= 1) p += __shfl_down(p, off);
    if (t == 0) out[g] = 1.f / (1.f + expf(-(p + bl2[0])));
}

extern "C" void kernel_launch(void* const* d_in, const int* in_sizes, int n_in,
                              void* d_out, int out_size, void* d_ws, size_t ws_size,
                              hipStream_t stream) {
    const float* x   = (const float*)d_in[0];
    const int* ei    = (const int*)d_in[1];
    const int* batch = (const int*)d_in[2];
    const float* W1  = (const float*)d_in[3];
    const float* b1  = (const float*)d_in[4];
    const float* W2  = (const float*)d_in[5];
    const float* b2  = (const float*)d_in[6];
    const float* Wl1 = (const float*)d_in[7];
    const float* bl1 = (const float*)d_in[8];
    const float* Wl2 = (const float*)d_in[9];
    const float* bl2 = (const float*)d_in[10];
    float* out = (float*)d_out;

    const int N = in_sizes[2];         // 20000
    const int E = in_sizes[1] / 2;     // 320000
    const int G = 64;
    const int* src = ei;
    const int* dst = ei + E;

    // ---- workspace carve ----
    char* base = (char*)d_ws;
    size_t off = 0;
    auto carve = [&](size_t bytes) -> char* {
        char* p = base + off;
        off = (off + bytes + 15) & ~(size_t)15;
        return p;
    };
    // zeroed region first: deg[N], fillc[N], gsum[G*128]
    int*   deg    = (int*)carve((size_t)N * 4);
    int*   fillc  = (int*)carve((size_t)N * 4);
    float* gsum   = (float*)carve((size_t)G * 128 * 4);
    size_t zero_bytes = (size_t)(2 * N + G * 128) * 4;
    int*   rowptr = (int*)carve((size_t)(N + 1) * 4);
    int*   csr    = (int*)carve((size_t)E * 4);
    float* dinv   = (float*)carve((size_t)N * 4);
    int*   gstart = (int*)carve((size_t)(G + 1) * 4);
    unsigned short* w1th = (unsigned short*)carve((size_t)256 * 256 * 2);
    unsigned short* w1tl = (unsigned short*)carve((size_t)256 * 256 * 2);
    unsigned short* w2th = (unsigned short*)carve((size_t)128 * 256 * 2);
    unsigned short* w2tl = (unsigned short*)carve((size_t)128 * 256 * 2);
    unsigned short* xh   = (unsigned short*)carve((size_t)N * 256 * 2);
    unsigned short* h    = (unsigned short*)carve((size_t)N * 256 * 2);
    unsigned short* o1h  = (unsigned short*)carve((size_t)N * 256 * 2);
    // lifetime-disjoint aliases:
    unsigned short* t = h;             // t [N][128] bf16; h dead after gather256
    float* out2 = (float*)xh;          // out2 [N][128] fp32 (10.24MB); xh dead after gemm1

    hipMemsetAsync(d_ws, 0, zero_bytes, stream);

    // fused prep: convert_x | bounds | deg | convert_w
    const int CXB = (int)(((size_t)N * 64 + 255) / 256);        // 5000
    const int BNB = (N + 255) / 256;                            // 79
    const int DGB = (E + 255) / 256;                            // 1250
    const int CWB = (256 * 256 + 128 * 256 + 255) / 256;        // 384
    prep_kernel<<<CXB + BNB + DGB + CWB, 256, 0, stream>>>(
        x, xh, batch, gstart, dst, deg, W1, w1th, w1tl, W2, w2th, w2tl,
        N, E, G, CXB, BNB, DGB);

    scan_kernel<<<1, 1024, 0, stream>>>(deg, rowptr, dinv, N);
    fill_kernel<<<(E + 255) / 256, 256, 0, stream>>>(src, dst, rowptr, fillc, csr, E);

    // layer 1
    {
        dim3 grid(256 / 64, (N + 127) / 128);
        gemm_mfma<<<grid, 256, 0, stream>>>(xh, w1th, w1tl, h, N, 256, 256);
        gather256_kernel<<<(N + 3) / 4, 256, 0, stream>>>(h, csr, rowptr, dinv, b1, o1h, N);
    }
    // layer 2
    {
        dim3 grid(128 / 64, (N + 127) / 128);
        gemm_mfma<<<grid, 256, 0, stream>>>(o1h, w2th, w2tl, t, N, 256, 128);
        gather128_kernel<<<(N + 3) / 4, 256, 0, stream>>>(t, csr, rowptr, dinv, b2, out2, N);
    }
    // pool + head
    pool_kernel<<<G * 8, 256, 0, stream>>>(out2, gstart, gsum);
    head_kernel<<<G, 64, 0, stream>>>(gsum, gstart, Wl1, bl1, Wl2, bl2, out);
}

// Round 6
// 230.338 us; speedup vs baseline: 7.3276x; 1.0409x over previous
//
#include <hip/hip_runtime.h>
#include <hip/hip_bf16.h>
#include <math.h>

typedef __attribute__((ext_vector_type(8))) short bf16x8;
typedef __attribute__((ext_vector_type(4))) short bf16x4;
typedef __attribute__((ext_vector_type(4))) float f32x4;

__device__ __forceinline__ unsigned short f2bf(float f) {
    unsigned int u = __float_as_uint(f);
    unsigned int r = (u + 0x7FFFu + ((u >> 16) & 1u)) >> 16;
    return (unsigned short)r;
}
__device__ __forceinline__ float bf2f(unsigned short h) {
    return __uint_as_float(((unsigned int)h) << 16);
}
__device__ __forceinline__ float bfe(short s) {
    return __uint_as_float(((unsigned int)(unsigned short)s) << 16);
}

__device__ __forceinline__ void load_lds16(const unsigned short* g, unsigned short* l) {
    __builtin_amdgcn_global_load_lds(
        (const __attribute__((address_space(1))) unsigned int*)g,
        (__attribute__((address_space(3))) unsigned int*)l, 16, 0, 0);
}

// ================= fused prep: convert_x | bounds | deg | convert_w =================
__global__ __launch_bounds__(256) void prep_kernel(const float* __restrict__ x,
                                                   unsigned short* __restrict__ xh,
                                                   const int* __restrict__ batch,
                                                   int* __restrict__ gstart,
                                                   const int* __restrict__ dst,
                                                   int* __restrict__ deg,
                                                   const float* __restrict__ W1,
                                                   unsigned short* __restrict__ w1th,
                                                   unsigned short* __restrict__ w1tl,
                                                   const float* __restrict__ W2,
                                                   unsigned short* __restrict__ w2th,
                                                   unsigned short* __restrict__ w2tl,
                                                   int N, int E, int G,
                                                   int CXB, int BNB, int DGB) {
    int b = blockIdx.x;
    int tid = threadIdx.x;
    if (b < CXB) {
        size_t idx = (size_t)b * 256 + tid;
        size_t total4 = (size_t)N * 64;
        if (idx < total4) {
            float4 v = ((const float4*)x)[idx];
            ushort4 o;
            o.x = f2bf(v.x); o.y = f2bf(v.y); o.z = f2bf(v.z); o.w = f2bf(v.w);
            ((ushort4*)xh)[idx] = o;
        }
        return;
    }
    b -= CXB;
    if (b < BNB) {
        int i = b * 256 + tid;
        if (i >= N) return;
        int bb = batch[i];
        if (i == 0) { for (int g = 0; g <= bb; g++) gstart[g] = 0; }
        else { int bp = batch[i - 1]; for (int g = bp + 1; g <= bb; g++) gstart[g] = i; }
        if (i == N - 1) { for (int g = bb + 1; g <= G; g++) gstart[g] = N; }
        return;
    }
    b -= BNB;
    if (b < DGB) {
        int e = b * 256 + tid;
        if (e < E) atomicAdd(&deg[dst[e]], 1);
        return;
    }
    b -= DGB;
    {
        int idx = b * 256 + tid;
        if (idx < 256 * 256) {
            int m = idx >> 8, k = idx & 255;
            float w = W1[(size_t)k * 256 + m];
            unsigned short hi = f2bf(w);
            w1th[idx] = hi;
            w1tl[idx] = f2bf(w - bf2f(hi));
        } else if (idx < 256 * 256 + 128 * 256) {
            int j = idx - 256 * 256;
            int m = j >> 8, k = j & 255;
            float w = W2[(size_t)k * 128 + m];
            unsigned short hi = f2bf(w);
            w2th[j] = hi;
            w2tl[j] = f2bf(w - bf2f(hi));
        }
    }
}

// ---------------- exclusive scan of deg -> rowptr, + dinv ----------------
__global__ __launch_bounds__(1024) void scan_kernel(const int* __restrict__ deg,
                                                    int* __restrict__ rowptr,
                                                    float* __restrict__ dinv, int N) {
    __shared__ int sums[1024];
    int t = threadIdx.x;
    int chunk = (N + 1023) >> 10;
    int start = t * chunk;
    int end = start + chunk;
    if (start > N) start = N;
    if (end > N) end = N;
    int s = 0;
    for (int i = start; i < end; i++) s += deg[i];
    sums[t] = s;
    __syncthreads();
    for (int off = 1; off < 1024; off <<= 1) {
        int v = (t >= off) ? sums[t - off] : 0;
        __syncthreads();
        sums[t] += v;
        __syncthreads();
    }
    int run = (t == 0) ? 0 : sums[t - 1];
    for (int i = start; i < end; i++) {
        int d = deg[i];
        rowptr[i] = run; run += d;
        dinv[i] = rsqrtf((float)d + 1.0f);
    }
    if (t == 1023) rowptr[N] = run;
}

// ---------------- shared MFMA GEMM body (128x64 tile, BK=32, hi/lo weights) ----------------
__device__ __forceinline__ void gemm_body(const unsigned short* __restrict__ A,
                                          const unsigned short* __restrict__ Bth,
                                          const unsigned short* __restrict__ Btl,
                                          unsigned short* __restrict__ C,
                                          int N, int K, int M, int bx, int by,
                                          unsigned short* As, unsigned short* Bhs,
                                          unsigned short* Bls) {
    int tid = threadIdx.x;
    int wave = tid >> 6, lane = tid & 63;
    int quad = lane >> 4, m16 = lane & 15;
    int r0 = by * 128, c0 = bx * 64;
    int srow = lane >> 2;
    int skoff = (lane & 3) * 8;

    f32x4 acc[2][4];
#pragma unroll
    for (int rg = 0; rg < 2; rg++)
#pragma unroll
        for (int ct = 0; ct < 4; ct++) acc[rg][ct] = (f32x4){0.f, 0.f, 0.f, 0.f};

    for (int kb = 0; kb < K; kb += 32) {
#pragma unroll
        for (int i = 0; i < 2; i++) {
            int brow = wave * 32 + i * 16 + srow;
            int grow = r0 + brow; if (grow >= N) grow = N - 1;
            load_lds16(A + (size_t)grow * K + kb + skoff, As + (wave * 32 + i * 16) * 32);
        }
        {
            int bcol = wave * 16 + srow;
            size_t goff = (size_t)(c0 + bcol) * K + kb + skoff;
            load_lds16(Bth + goff, Bhs + (wave * 16) * 32);
            load_lds16(Btl + goff, Bls + (wave * 16) * 32);
        }
        __syncthreads();
        bf16x8 af[2], bh[4], bl[4];
#pragma unroll
        for (int rg = 0; rg < 2; rg++)
            af[rg] = *(const bf16x8*)(As + (wave * 32 + rg * 16 + m16) * 32 + quad * 8);
#pragma unroll
        for (int ct = 0; ct < 4; ct++) {
            bh[ct] = *(const bf16x8*)(Bhs + (ct * 16 + m16) * 32 + quad * 8);
            bl[ct] = *(const bf16x8*)(Bls + (ct * 16 + m16) * 32 + quad * 8);
        }
#pragma unroll
        for (int rg = 0; rg < 2; rg++)
#pragma unroll
            for (int ct = 0; ct < 4; ct++) {
                acc[rg][ct] = __builtin_amdgcn_mfma_f32_16x16x32_bf16(af[rg], bh[ct], acc[rg][ct], 0, 0, 0);
                acc[rg][ct] = __builtin_amdgcn_mfma_f32_16x16x32_bf16(af[rg], bl[ct], acc[rg][ct], 0, 0, 0);
            }
        __syncthreads();
    }
#pragma unroll
    for (int rg = 0; rg < 2; rg++) {
#pragma unroll
        for (int ct = 0; ct < 4; ct++) {
            int col = c0 + ct * 16 + m16;
#pragma unroll
            for (int r = 0; r < 4; r++) {
                int row = r0 + wave * 32 + rg * 16 + quad * 4 + r;
                if (row < N) C[(size_t)row * M + col] = f2bf(acc[rg][ct][r]);
            }
        }
    }
}

// ---------------- merged: CSR fill + layer-1 GEMM (independent, co-scheduled) ----------------
__global__ __launch_bounds__(256) void fill_gemm1_kernel(const int* __restrict__ src,
                                                         const int* __restrict__ dst,
                                                         const int* __restrict__ rowptr,
                                                         int* __restrict__ fillc,
                                                         int* __restrict__ csr,
                                                         const unsigned short* __restrict__ A,
                                                         const unsigned short* __restrict__ Bth,
                                                         const unsigned short* __restrict__ Btl,
                                                         unsigned short* __restrict__ C,
                                                         int N, int E, int FB) {
    __shared__ unsigned short As[128 * 32];
    __shared__ unsigned short Bhs[64 * 32];
    __shared__ unsigned short Bls[64 * 32];
    if ((int)blockIdx.x < FB) {
        int e = blockIdx.x * 256 + threadIdx.x;
        if (e < E) {
            int d = dst[e];
            int pos = rowptr[d] + atomicAdd(&fillc[d], 1);
            csr[pos] = src[e];
        }
        return;
    }
    int gb = blockIdx.x - FB;
    int bx = gb & 3, by = gb >> 2;          // M=256 -> 4 col tiles
    gemm_body(A, Bth, Btl, C, N, 256, 256, bx, by, As, Bhs, Bls);
}

// ---------------- layer-2 GEMM ----------------
__global__ __launch_bounds__(256) void gemm2_kernel(const unsigned short* __restrict__ A,
                                                    const unsigned short* __restrict__ Bth,
                                                    const unsigned short* __restrict__ Btl,
                                                    unsigned short* __restrict__ C, int N) {
    __shared__ unsigned short As[128 * 32];
    __shared__ unsigned short Bhs[64 * 32];
    __shared__ unsigned short Bls[64 * 32];
    gemm_body(A, Bth, Btl, C, N, 256, 128, blockIdx.x, blockIdx.y, As, Bhs, Bls);
}

// ---------------- gather 256 ch: 8 neighbors in flight per wave ----------------
__global__ __launch_bounds__(256) void gather256_kernel(const unsigned short* __restrict__ h,
                                                        const int* __restrict__ csr_src,
                                                        const int* __restrict__ rowptr,
                                                        const float* __restrict__ dinv,
                                                        const float* __restrict__ bias,
                                                        unsigned short* __restrict__ out, int N) {
    int node = blockIdx.x * 4 + (threadIdx.x >> 6);
    if (node >= N) return;
    int lane = threadIdx.x & 63;
    int half = lane >> 5, hl = lane & 31;
    int beg = rowptr[node], end = rowptr[node + 1];
    float a[8] = {0, 0, 0, 0, 0, 0, 0, 0};
    int j = beg;
    for (; j + 7 < end; j += 8) {
        int s0 = csr_src[j + half], s1 = csr_src[j + 2 + half];
        int s2 = csr_src[j + 4 + half], s3 = csr_src[j + 6 + half];
        float w0 = dinv[s0], w1 = dinv[s1], w2 = dinv[s2], w3 = dinv[s3];
        bf16x8 v0 = *(const bf16x8*)(h + (size_t)s0 * 256 + hl * 8);
        bf16x8 v1 = *(const bf16x8*)(h + (size_t)s1 * 256 + hl * 8);
        bf16x8 v2 = *(const bf16x8*)(h + (size_t)s2 * 256 + hl * 8);
        bf16x8 v3 = *(const bf16x8*)(h + (size_t)s3 * 256 + hl * 8);
#pragma unroll
        for (int i = 0; i < 8; i++)
            a[i] += bfe(v0[i]) * w0 + bfe(v1[i]) * w1 + bfe(v2[i]) * w2 + bfe(v3[i]) * w3;
    }
    for (; j + 1 < end; j += 2) {
        int s0 = csr_src[j + half];
        float w0 = dinv[s0];
        bf16x8 v0 = *(const bf16x8*)(h + (size_t)s0 * 256 + hl * 8);
#pragma unroll
        for (int i = 0; i < 8; i++) a[i] += bfe(v0[i]) * w0;
    }
    if (j < end && half == 0) {
        int s0 = csr_src[j];
        float w0 = dinv[s0];
        bf16x8 v0 = *(const bf16x8*)(h + (size_t)s0 * 256 + hl * 8);
#pragma unroll
        for (int i = 0; i < 8; i++) a[i] += bfe(v0[i]) * w0;
    }
#pragma unroll
    for (int i = 0; i < 8; i++) a[i] += __shfl_down(a[i], 32);
    if (half == 0) {
        float dd = dinv[node];
        bf16x8 hv = *(const bf16x8*)(h + (size_t)node * 256 + hl * 8);
        float4 bv0 = ((const float4*)bias)[hl * 2];
        float4 bv1 = ((const float4*)bias)[hl * 2 + 1];
        float bvf[8] = {bv0.x, bv0.y, bv0.z, bv0.w, bv1.x, bv1.y, bv1.z, bv1.w};
        bf16x8 o;
#pragma unroll
        for (int i = 0; i < 8; i++)
            o[i] = (short)f2bf(fmaxf((a[i] + bfe(hv[i]) * dd) * dd + bvf[i], 0.f));
        ((bf16x8*)(out + (size_t)node * 256))[hl] = o;
    }
}

// ---------------- gather 128 ch: 8 neighbors in flight, bf16 out ----------------
__global__ __launch_bounds__(256) void gather128_kernel(const unsigned short* __restrict__ t,
                                                        const int* __restrict__ csr_src,
                                                        const int* __restrict__ rowptr,
                                                        const float* __restrict__ dinv,
                                                        const float* __restrict__ bias,
                                                        unsigned short* __restrict__ out2, int N) {
    int node = blockIdx.x * 4 + (threadIdx.x >> 6);
    if (node >= N) return;
    int lane = threadIdx.x & 63;
    int half = lane >> 5, hl = lane & 31;
    int beg = rowptr[node], end = rowptr[node + 1];
    float a[4] = {0, 0, 0, 0};
    int j = beg;
    for (; j + 7 < end; j += 8) {
        int s0 = csr_src[j + half], s1 = csr_src[j + 2 + half];
        int s2 = csr_src[j + 4 + half], s3 = csr_src[j + 6 + half];
        float w0 = dinv[s0], w1 = dinv[s1], w2 = dinv[s2], w3 = dinv[s3];
        bf16x4 v0 = *(const bf16x4*)(t + (size_t)s0 * 128 + hl * 4);
        bf16x4 v1 = *(const bf16x4*)(t + (size_t)s1 * 128 + hl * 4);
        bf16x4 v2 = *(const bf16x4*)(t + (size_t)s2 * 128 + hl * 4);
        bf16x4 v3 = *(const bf16x4*)(t + (size_t)s3 * 128 + hl * 4);
#pragma unroll
        for (int i = 0; i < 4; i++)
            a[i] += bfe(v0[i]) * w0 + bfe(v1[i]) * w1 + bfe(v2[i]) * w2 + bfe(v3[i]) * w3;
    }
    for (; j + 1 < end; j += 2) {
        int s0 = csr_src[j + half];
        float w0 = dinv[s0];
        bf16x4 v0 = *(const bf16x4*)(t + (size_t)s0 * 128 + hl * 4);
#pragma unroll
        for (int i = 0; i < 4; i++) a[i] += bfe(v0[i]) * w0;
    }
    if (j < end && half == 0) {
        int s0 = csr_src[j];
        float w0 = dinv[s0];
        bf16x4 v0 = *(const bf16x4*)(t + (size_t)s0 * 128 + hl * 4);
#pragma unroll
        for (int i = 0; i < 4; i++) a[i] += bfe(v0[i]) * w0;
    }
#pragma unroll
    for (int i = 0; i < 4; i++) a[i] += __shfl_down(a[i], 32);
    if (half == 0) {
        float dd = dinv[node];
        bf16x4 hv = *(const bf16x4*)(t + (size_t)node * 128 + hl * 4);
        float4 bv = ((const float4*)bias)[hl];
        bf16x4 o;
        o[0] = (short)f2bf(fmaxf((a[0] + bfe(hv[0]) * dd) * dd + bv.x, 0.f));
        o[1] = (short)f2bf(fmaxf((a[1] + bfe(hv[1]) * dd) * dd + bv.y, 0.f));
        o[2] = (short)f2bf(fmaxf((a[2] + bfe(hv[2]) * dd) * dd + bv.z, 0.f));
        o[3] = (short)f2bf(fmaxf((a[3] + bfe(hv[3]) * dd) * dd + bv.w, 0.f));
        ((bf16x4*)(out2 + (size_t)node * 128))[hl] = o;
    }
}

// ---------------- parallel pool: 8 slices/graph, bf16 in, LDS reduce, 128 atomics/block ----------------
__global__ __launch_bounds__(256) void pool_kernel(const unsigned short* __restrict__ out2,
                                                   const int* __restrict__ gstart,
                                                   float* __restrict__ gsum) {
    int g = blockIdx.x >> 3, slice = blockIdx.x & 7;
    int wave = threadIdx.x >> 6, lane = threadIdx.x & 63;
    int gs = gstart[g], ge = gstart[g + 1];
    float s0 = 0.f, s1 = 0.f;
    for (int i = gs + slice * 4 + wave; i < ge; i += 32) {
        ushort2 v = ((const ushort2*)(out2 + (size_t)i * 128))[lane];
        s0 += bf2f(v.x); s1 += bf2f(v.y);
    }
    __shared__ float red[4][128];
    red[wave][lane * 2] = s0;
    red[wave][lane * 2 + 1] = s1;
    __syncthreads();
    if (wave == 0) {
        float m0 = red[0][lane * 2] + red[1][lane * 2] + red[2][lane * 2] + red[3][lane * 2];
        float m1 = red[0][lane * 2 + 1] + red[1][lane * 2 + 1] + red[2][lane * 2 + 1] + red[3][lane * 2 + 1];
        if (m0 != 0.f) atomicAdd(&gsum[g * 128 + lane * 2], m0);
        if (m1 != 0.f) atomicAdd(&gsum[g * 128 + lane * 2 + 1], m1);
    }
}

// ---------------- head ----------------
__global__ void head_kernel(const float* __restrict__ gsum, const int* __restrict__ gstart,
                            const float* __restrict__ Wl1, const float* __restrict__ bl1,
                            const float* __restrict__ Wl2, const float* __restrict__ bl2,
                            float* __restrict__ out) {
    int g = blockIdx.x;
    int t = threadIdx.x;  // 64 threads
    __shared__ float gv[128];
    float cnt = fmaxf((float)(gstart[g + 1] - gstart[g]), 1.0f);
    gv[t]      = gsum[g * 128 + t] / cnt;
    gv[t + 64] = gsum[g * 128 + 64 + t] / cnt;
    __syncthreads();
    float acc = bl1[t];
    for (int k = 0; k < 128; k++) acc += gv[k] * Wl1[k * 64 + t];
    acc = fmaxf(acc, 0.f);
    float p = acc * Wl2[t];
#pragma unroll
    for (int off = 32; off; off >>= 1) p += __shfl_down(p, off);
    if (t == 0) out[g] = 1.f / (1.f + expf(-(p + bl2[0])));
}

extern "C" void kernel_launch(void* const* d_in, const int* in_sizes, int n_in,
                              void* d_out, int out_size, void* d_ws, size_t ws_size,
                              hipStream_t stream) {
    const float* x   = (const float*)d_in[0];
    const int* ei    = (const int*)d_in[1];
    const int* batch = (const int*)d_in[2];
    const float* W1  = (const float*)d_in[3];
    const float* b1  = (const float*)d_in[4];
    const float* W2  = (const float*)d_in[5];
    const float* b2  = (const float*)d_in[6];
    const float* Wl1 = (const float*)d_in[7];
    const float* bl1 = (const float*)d_in[8];
    const float* Wl2 = (const float*)d_in[9];
    const float* bl2 = (const float*)d_in[10];
    float* out = (float*)d_out;

    const int N = in_sizes[2];         // 20000
    const int E = in_sizes[1] / 2;     // 320000
    const int G = 64;
    const int* src = ei;
    const int* dst = ei + E;

    // ---- workspace carve ----
    char* base = (char*)d_ws;
    size_t off = 0;
    auto carve = [&](size_t bytes) -> char* {
        char* p = base + off;
        off = (off + bytes + 15) & ~(size_t)15;
        return p;
    };
    int*   deg    = (int*)carve((size_t)N * 4);
    int*   fillc  = (int*)carve((size_t)N * 4);
    float* gsum   = (float*)carve((size_t)G * 128 * 4);
    size_t zero_bytes = (size_t)(2 * N + G * 128) * 4;
    int*   rowptr = (int*)carve((size_t)(N + 1) * 4);
    int*   csr    = (int*)carve((size_t)E * 4);
    float* dinv   = (float*)carve((size_t)N * 4);
    int*   gstart = (int*)carve((size_t)(G + 1) * 4);
    unsigned short* w1th = (unsigned short*)carve((size_t)256 * 256 * 2);
    unsigned short* w1tl = (unsigned short*)carve((size_t)256 * 256 * 2);
    unsigned short* w2th = (unsigned short*)carve((size_t)128 * 256 * 2);
    unsigned short* w2tl = (unsigned short*)carve((size_t)128 * 256 * 2);
    unsigned short* xh   = (unsigned short*)carve((size_t)N * 256 * 2);
    unsigned short* h    = (unsigned short*)carve((size_t)N * 256 * 2);
    unsigned short* o1h  = (unsigned short*)carve((size_t)N * 256 * 2);
    // lifetime-disjoint aliases:
    unsigned short* t    = h;                       // t [N][128] bf16; h dead after gather256
    unsigned short* out2 = xh;                      // out2 [N][128] bf16; xh dead after gemm1

    hipMemsetAsync(d_ws, 0, zero_bytes, stream);

    // fused prep: convert_x | bounds | deg | convert_w
    const int CXB = (int)(((size_t)N * 64 + 255) / 256);
    const int BNB = (N + 255) / 256;
    const int DGB = (E + 255) / 256;
    const int CWB = (256 * 256 + 128 * 256 + 255) / 256;
    prep_kernel<<<CXB + BNB + DGB + CWB, 256, 0, stream>>>(
        x, xh, batch, gstart, dst, deg, W1, w1th, w1tl, W2, w2th, w2tl,
        N, E, G, CXB, BNB, DGB);

    scan_kernel<<<1, 1024, 0, stream>>>(deg, rowptr, dinv, N);

    // merged CSR-fill + layer-1 GEMM
    const int FB = (E + 255) / 256;                       // 1250 fill blocks
    const int GB1 = 4 * ((N + 127) / 128);                // 628 gemm blocks
    fill_gemm1_kernel<<<FB + GB1, 256, 0, stream>>>(src, dst, rowptr, fillc, csr,
                                                    xh, w1th, w1tl, h, N, E, FB);

    gather256_kernel<<<(N + 3) / 4, 256, 0, stream>>>(h, csr, rowptr, dinv, b1, o1h, N);

    {
        dim3 grid(2, (N + 127) / 128);
        gemm2_kernel<<<grid, 256, 0, stream>>>(o1h, w2th, w2tl, t, N);
    }
    gather128_kernel<<<(N + 3) / 4, 256, 0, stream>>>(t, csr, rowptr, dinv, b2, out2, N);

    pool_kernel<<<G * 8, 256, 0, stream>>>(out2, gstart, gsum);
    head_kernel<<<G, 64, 0, stream>>>(gsum, gstart, Wl1, bl1, Wl2, bl2, out);
}